// Round 12
// baseline (2251.840 us; speedup 1.0000x reference)
//
#include <hip/hip_runtime.h>
#include <cstdint>
#include <cstddef>

#define BATCH 8
#define NPTS  8192
#define MCENT 1024
#define KNN   32
#define CFEAT 64
#define EPS_F 1e-5f

// Workspace layout (70 MiB):
//   gidx : [0, 1MiB)          part : [1MiB, 5MiB)
//   bn   : [5MiB, +2KiB)      fps dist : [5MiB+64KiB, +256KiB)  cst : after
//   h1   : [6MiB, 70MiB)      f32 [262144][64], reused in-place as h2
#define WS_NEED 73400320ull

// ---------------------------------------------------------------- fast erf GELU
__device__ __forceinline__ float erf_fast(float x) {
  float a = fabsf(x);
  float t = __builtin_amdgcn_rcpf(fmaf(0.3275911f, a, 1.0f));
  float p = fmaf(1.061405429f, t, -1.453152027f);
  p = fmaf(p, t, 1.421413741f);
  p = fmaf(p, t, -0.284496736f);
  p = fmaf(p, t, 0.254829592f);
  float e = __expf(-a * a);
  float y = fmaf(-p * t, e, 1.0f);
  return copysignf(y, x);
}
__device__ __forceinline__ float gelu_f(float x) {
  return 0.5f * x * (1.0f + erf_fast(x * 0.70710678118654752440f));
}

// DPP wave64 reduce helpers.
template<int CTRL>
__device__ __forceinline__ float dpp_max_step(float v) {
  int s = __builtin_amdgcn_update_dpp(__float_as_int(v), __float_as_int(v),
                                      CTRL, 0xf, 0xf, false);
  return fmaxf(v, __int_as_float(s));
}
__device__ __forceinline__ float wave_max_dpp(float v) {
  v = dpp_max_step<0x111>(v);
  v = dpp_max_step<0x112>(v);
  v = dpp_max_step<0x114>(v);
  v = dpp_max_step<0x118>(v);
  v = dpp_max_step<0x142>(v);
  v = dpp_max_step<0x143>(v);
  return v;                    // lane 63 = wave max
}
template<int CTRL>
__device__ __forceinline__ unsigned long long dpp_min64_step(unsigned long long v) {
  int lo = __builtin_amdgcn_update_dpp((int)(unsigned)(v & 0xffffffffull),
                                       (int)(unsigned)(v & 0xffffffffull),
                                       CTRL, 0xf, 0xf, false);
  int hi = __builtin_amdgcn_update_dpp((int)(unsigned)(v >> 32),
                                       (int)(unsigned)(v >> 32),
                                       CTRL, 0xf, 0xf, false);
  unsigned long long o = (((unsigned long long)(unsigned)hi) << 32) | (unsigned)lo;
  return o < v ? o : v;
}
__device__ __forceinline__ unsigned long long wave_min64_dpp(unsigned long long v) {
  v = dpp_min64_step<0x111>(v);
  v = dpp_min64_step<0x112>(v);
  v = dpp_min64_step<0x114>(v);
  v = dpp_min64_step<0x118>(v);
  v = dpp_min64_step<0x142>(v);
  v = dpp_min64_step<0x143>(v);
  return v;                    // lane 63 = wave min
}

// Channel-exchange tree steps, COMPILE-TIME bounds (rule #20).
// NOTE: 32-wide per-thread arrays max in GEMM-reduce kernels; keeping in[64]
// live across a chunk loop spills (R9/R11 post-mortems).
template<int M, int HALF>
__device__ __forceinline__ void tree_step(float* s_, float* q_, int lane) {
  bool up = (lane & M) != 0;
#pragma unroll
  for (int j = 0; j < HALF; ++j) {
    float ks = up ? s_[j+HALF] : s_[j];
    float ds = up ? s_[j]      : s_[j+HALF];
    s_[j] = ks + __shfl_xor(ds, M, 64);
    float kq = up ? q_[j+HALF] : q_[j];
    float dq = up ? q_[j]      : q_[j+HALF];
    q_[j] = kq + __shfl_xor(dq, M, 64);
  }
}
template<int M, int HALF>
__device__ __forceinline__ void ptree_step(float* g_, int kbit) {
  bool up = (kbit & M) != 0;
#pragma unroll
  for (int j = 0; j < HALF; ++j) {
    float kv = up ? g_[j+HALF] : g_[j];
    float dv = up ? g_[j]      : g_[j+HALF];
    g_[j] = fmaxf(kv, __shfl_xor(dv, M, 64));
  }
}

// ---------------------------------------------------------------- 1. MEGA kernel
// One dispatch per 64-step FPS phase; role-split blocks use idle CUs:
//   blk 0-3    : FPS, TWO batches per block (waves 0-3 / 4-7) — stalls of one
//                batch hide under the other's VALU work on the same CU.
//   blk 4-67   : ball query, phase s0-64
//   blk 68-99  : layer-1,   phase s0-128
//   blk 100-131: L1 BN stats, phase s0-192
// Same-stream dispatch ordering guarantees producer visibility.
#define FPS_STEPS 64
#define BQCAP 512
__global__ __launch_bounds__(512, 2) void mega_kernel(
    const float* __restrict__ xyz, float* __restrict__ new_xyz,
    float* __restrict__ dist_ws, float* __restrict__ cst, int s0,
    int* __restrict__ gidx, const float* __restrict__ feats,
    const float* __restrict__ W1, const float* __restrict__ b1v,
    float* __restrict__ h1, float* __restrict__ part)
{
  __shared__ float outb2[2][FPS_STEPS * 3];        // 1.5 KiB (fps)
  __shared__ unsigned long long keys[2][8];
  __shared__ unsigned long long list[8][BQCAP];    // 32 KiB (bq)
  __shared__ float ls[512], lss[512];              // 4 KiB (stats)
  int blk = blockIdx.x, t = threadIdx.x;

  if (blk < 4) {
    // ---------------- FPS role: 2 batches/block, 32 pts/thread --------------
    // Bit-exact jnp arithmetic; tie-breaks: strict > over ascending slots
    // (thread t owns contiguous [32t,32t+32)), ballot lowest lane, u64 key
    // (dist<<32 | 8191-idx) across the batch's 4 waves.
    if (s0 >= MCENT) return;
    int half = t >> 8;                   // 0 = batch A (waves 0-3), 1 = B
    int bb = blk * 2 + half;             // batch 0..7
    int tb = t & 255;                    // batch-local thread
    int lane = t & 63, wv = t >> 6;      // wv 0..7
    const float* xb = xyz + (size_t)bb * NPTS * 3;

    float px[32], py[32], pz[32], dist[32];
    {
      const float4* src = (const float4*)(xb + (size_t)tb * 96);
#pragma unroll
      for (int c4 = 0; c4 < 4; ++c4) {
        float4 buf[6];
#pragma unroll
        for (int i = 0; i < 6; ++i) buf[i] = src[c4*6 + i];
        const float* f = (const float*)buf;
#pragma unroll
        for (int i = 0; i < 8; ++i) {
          px[c4*8+i] = f[i*3+0]; py[c4*8+i] = f[i*3+1]; pz[c4*8+i] = f[i*3+2];
        }
      }
    }
    float* dw = dist_ws + (size_t)bb * NPTS + (size_t)tb * 32;
    float cx, cy, cz;
    if (s0 == 0) {
#pragma unroll
      for (int i = 0; i < 32; ++i) dist[i] = __builtin_inff();
      cx = xb[0]; cy = xb[1]; cz = xb[2];
    } else {
#pragma unroll
      for (int i = 0; i < 8; ++i) {
        float4 d = *(const float4*)(dw + i * 4);
        dist[i*4+0]=d.x; dist[i*4+1]=d.y; dist[i*4+2]=d.z; dist[i*4+3]=d.w;
      }
      cx = cst[bb*3+0]; cy = cst[bb*3+1]; cz = cst[bb*3+2];
    }

    for (int s = 0; s < FPS_STEPS; ++s) {
      if (tb == 0) {
        outb2[half][s*3+0] = cx; outb2[half][s*3+1] = cy; outb2[half][s*3+2] = cz;
      }
      float bd = -1.0f; int bslot = 0;
#pragma unroll
      for (int i = 0; i < 32; ++i) {
        float dx = __fsub_rn(px[i], cx);
        float dy = __fsub_rn(py[i], cy);
        float dz = __fsub_rn(pz[i], cz);
        float d  = __fadd_rn(__fadd_rn(__fmul_rn(dx,dx), __fmul_rn(dy,dy)), __fmul_rn(dz,dz));
        float nd = fminf(dist[i], d);
        dist[i] = nd;
        if (nd > bd) { bd = nd; bslot = i; }    // strict >: first max in idx order
      }
      float w = wave_max_dpp(bd);
      float wmax = __int_as_float(__builtin_amdgcn_readlane(__float_as_int(w), 63));
      unsigned long long mk = __ballot(bd == wmax);
      int sl = __ffsll((long long)mk) - 1;      // lowest lane = lowest idx
      int widx = __builtin_amdgcn_readlane(tb * 32 + bslot, sl);
      if (lane == 0)
        keys[s & 1][wv] = (((unsigned long long)__float_as_uint(wmax)) << 32)
                          | (unsigned)(8191 - widx);
      __syncthreads();
      int wb = half * 4;
      unsigned long long bk = keys[s & 1][wb];
#pragma unroll
      for (int w2 = 1; w2 < 4; ++w2) {
        unsigned long long o = keys[s & 1][wb + w2];
        if (o > bk) bk = o;
      }
      int idx = 8191 - (int)(unsigned)(bk & 0xffffffffull);
      int uidx = __builtin_amdgcn_readfirstlane(idx);   // uniform -> s_load
      cx = xb[uidx*3+0]; cy = xb[uidx*3+1]; cz = xb[uidx*3+2];
    }

#pragma unroll
    for (int i = 0; i < 8; ++i)
      *(float4*)(dw + i * 4) = make_float4(dist[i*4+0], dist[i*4+1],
                                           dist[i*4+2], dist[i*4+3]);
    if (tb == 0) { cst[bb*3+0] = cx; cst[bb*3+1] = cy; cst[bb*3+2] = cz; }
    __syncthreads();
    float* ob = new_xyz + (size_t)bb * MCENT * 3 + (size_t)s0 * 3;
    const float* mo = outb2[half];
    for (int i = tb; i < FPS_STEPS * 3; i += 256) ob[i] = mo[i];

  } else if (blk < 68) {
    // ---------------- Ball-query role: phase s0-64 --------------------------
    int ph = s0 - FPS_STEPS;
    if (ph < 0 || ph >= MCENT) return;
    int wv = t >> 6, lane = t & 63;
    int c  = (blk - 4) * 8 + wv;                 // 0..511
    int b  = c >> 6;
    int ci = ph + (c & 63);
    int gm = b * MCENT + ci;
    const float* cc = new_xyz + (size_t)gm * 3;
    float c0 = cc[0], c1 = cc[1], c2 = cc[2];
    float sc = __fadd_rn(__fadd_rn(__fmul_rn(c0,c0), __fmul_rn(c1,c1)), __fmul_rn(c2,c2));
    const float* xb = xyz + (size_t)b * NPTS * 3;

    unsigned cnt = 0;
    for (int j0 = 0; j0 < NPTS; j0 += 64) {
      int j = j0 + lane;
      float x = xb[j*3+0], y = xb[j*3+1], z = xb[j*3+2];
      float sx  = __fadd_rn(__fadd_rn(__fmul_rn(x,x), __fmul_rn(y,y)), __fmul_rn(z,z));
      float dot = __fadd_rn(__fadd_rn(__fmul_rn(c0,x), __fmul_rn(c1,y)), __fmul_rn(c2,z));
      float d2  = __fsub_rn(__fadd_rn(sc, sx), __fmul_rn(2.0f, dot));
      float dist = sqrtf(fmaxf(d2, 0.0f));
      bool in_ = (dist <= 0.5f);
      unsigned long long mask = __ballot(in_);
      unsigned off = (unsigned)__popcll(mask & ((1ull << lane) - 1ull));
      if (in_) {
        unsigned pos = cnt + off;
        if (pos < BQCAP)
          list[wv][pos] = (((unsigned long long)__float_as_uint(dist)) << 32) | (unsigned)j;
      }
      cnt += (unsigned)__popcll(mask);
    }
    if (cnt > BQCAP) cnt = BQCAP;

    unsigned long long e[8];
#pragma unroll
    for (int i = 0; i < 8; ++i) {
      unsigned pos = (unsigned)lane + ((unsigned)i << 6);
      e[i] = (pos < cnt) ? list[wv][pos] : ~0ull;
    }
#define CE_(a_, b_) { bool sw = e[b_] < e[a_]; \
                      unsigned long long lo_ = sw ? e[b_] : e[a_]; \
                      unsigned long long hi_ = sw ? e[a_] : e[b_]; \
                      e[a_] = lo_; e[b_] = hi_; }
    CE_(0,1) CE_(2,3) CE_(4,5) CE_(6,7)
    CE_(0,2) CE_(1,3) CE_(4,6) CE_(5,7)
    CE_(1,2) CE_(5,6)
    CE_(0,4) CE_(1,5) CE_(2,6) CE_(3,7)
    CE_(2,4) CE_(3,5)
    CE_(1,2) CE_(3,4) CE_(5,6)
#undef CE_

    int* gout = gidx + (size_t)gm * KNN;
    int first = 0;
    int kmax = (cnt < (unsigned)KNN) ? (int)cnt : KNN;
    for (int k = 0; k < KNN; ++k) {
      if (k < kmax) {
        unsigned long long wr = wave_min64_dpp(e[0]);
        unsigned lo32 = (unsigned)__builtin_amdgcn_readlane((int)(unsigned)(wr & 0xffffffffull), 63);
        unsigned hi32 = (unsigned)__builtin_amdgcn_readlane((int)(unsigned)(wr >> 32), 63);
        unsigned long long wmin = (((unsigned long long)hi32) << 32) | lo32;
        int idxv = (int)lo32;
        if (k == 0) first = idxv;
        if (lane == 0) gout[k] = idxv;
        bool win = (e[0] == wmin);
#pragma unroll
        for (int i = 0; i < 7; ++i) e[i] = win ? e[i+1] : e[i];
        e[7] = win ? ~0ull : e[7];
      } else {
        if (lane == 0) gout[k] = first;
      }
    }

  } else if (blk < 100) {
    // ---------------- Layer-1 role: phase s0-128 ----------------------------
    int ph = s0 - 2 * FPS_STEPS;
    if (ph < 0 || ph >= MCENT) return;
    int row = (blk - 68) * 512 + t;              // 0..16383
    int c   = row >> 5;                          // centroid seq 0..511
    int k   = row & 31;
    int b   = c >> 6;
    int ci  = ph + (c & 63);
    int p   = b * (MCENT * KNN) + ci * KNN + k;  // global h1 row
    int idx = gidx[p];
    const float* cc = new_xyz + (size_t)(b * MCENT + ci) * 3;
    const float* q  = xyz + (size_t)(b * NPTS + idx) * 3;
    float in[67];
    in[0] = q[0] - cc[0];
    in[1] = q[1] - cc[1];
    in[2] = q[2] - cc[2];
    const float* fr = feats + (size_t)(b * NPTS + idx) * CFEAT;
#pragma unroll
    for (int j = 0; j < 64; j += 4) {
      float4 v = *(const float4*)(fr + j);
      in[3+j] = v.x; in[4+j] = v.y; in[5+j] = v.z; in[6+j] = v.w;
    }
    float* orow = h1 + (size_t)p * 64;
    for (int o4 = 0; o4 < 16; ++o4) {
      const float* w0 = W1 + (size_t)(o4 * 4) * 67;
      float a0 = b1v[o4*4+0], a1 = b1v[o4*4+1], a2 = b1v[o4*4+2], a3 = b1v[o4*4+3];
#pragma unroll
      for (int j = 0; j < 67; ++j) {
        float x = in[j];
        a0 = fmaf(x, w0[j],       a0);
        a1 = fmaf(x, w0[67+j],    a1);
        a2 = fmaf(x, w0[134+j],   a2);
        a3 = fmaf(x, w0[201+j],   a3);
      }
      *(float4*)(orow + o4*4) = make_float4(a0, a1, a2, a3);
    }

  } else {
    // ---------------- L1 BN-stats role: phase s0-192 ------------------------
    int ph = s0 - 3 * FPS_STEPS;
    if (ph < 0 || ph >= MCENT) return;
    int sb = blk - 100;                          // 0..31
    int b  = sb >> 2;
    int rb = (sb & 3) * 512;
    int c  = t & 63, g = t >> 6;                 // 8 groups of 64
    size_t base = (size_t)b * (MCENT * KNN) + (size_t)ph * KNN + rb;
    float s = 0.0f, ss = 0.0f;
    for (int r = g; r < 512; r += 8) {
      float v = h1[(base + r) * 64 + c];
      s += v;
      ss = fmaf(v, v, ss);
    }
    ls[t] = s; lss[t] = ss;
    __syncthreads();
    if (g == 0) {
#pragma unroll
      for (int gg = 1; gg < 8; ++gg) { s += ls[gg*64 + c]; ss += lss[gg*64 + c]; }
      int pblk = (ph >> 6) * 32 + sb;            // 0..511
      part[(size_t)pblk * 128 + c]      = s;
      part[(size_t)pblk * 128 + 64 + c] = ss;
    }
  }
}

// ---------------------------------------------------------------- 4. Layer 2: BN1+GELU then W2, IN-PLACE
__global__ __launch_bounds__(256) void l2_kernel(
    float* __restrict__ h, const float* __restrict__ W,
    const float* __restrict__ bv, const float* __restrict__ bnp,
    const float* __restrict__ btp)
{
  int p = blockIdx.x * 256 + threadIdx.x;
  float* row = h + (size_t)p * 64;
  float in[64];
#pragma unroll
  for (int j = 0; j < 64; j += 4) {
    float4 v = *(const float4*)(row + j);
    in[j+0] = gelu_f((v.x - bnp[j+0]) * bnp[64+j+0] + btp[j+0]);
    in[j+1] = gelu_f((v.y - bnp[j+1]) * bnp[64+j+1] + btp[j+1]);
    in[j+2] = gelu_f((v.z - bnp[j+2]) * bnp[64+j+2] + btp[j+2]);
    in[j+3] = gelu_f((v.w - bnp[j+3]) * bnp[64+j+3] + btp[j+3]);
  }
  for (int o4 = 0; o4 < 16; ++o4) {
    const float* w0 = W + (size_t)(o4 * 4) * 64;
    float a0 = bv[o4*4+0], a1 = bv[o4*4+1], a2 = bv[o4*4+2], a3 = bv[o4*4+3];
#pragma unroll
    for (int j = 0; j < 64; ++j) {
      float x = in[j];
      a0 = fmaf(x, w0[j],      a0);
      a1 = fmaf(x, w0[64+j],   a1);
      a2 = fmaf(x, w0[128+j],  a2);
      a3 = fmaf(x, w0[192+j],  a3);
    }
    *(float4*)(row + o4*4) = make_float4(a0, a1, a2, a3);
  }
}

// ---------------------------------------------------------------- 5. Deterministic BN stats (layer 2)
template<int C>
__global__ __launch_bounds__(256) void stats_kernel(const float* __restrict__ h,
                                                    float* __restrict__ part)
{
  constexpr int G = 256 / C;
  int t = threadIdx.x;
  int c = t % C, g = t / C;
  const float* base = h + (size_t)blockIdx.x * 512 * C;
  float s = 0.0f, ss = 0.0f;
  for (int r = g; r < 512; r += G) {
    float v = base[(size_t)r * C + c];
    s += v;
    ss = fmaf(v, v, ss);
  }
  __shared__ float ls[256], lss[256];
  ls[t] = s; lss[t] = ss;
  __syncthreads();
  if (g == 0) {
    for (int gg = 1; gg < G; ++gg) { s += ls[gg*C + c]; ss += lss[gg*C + c]; }
    part[(size_t)blockIdx.x * (2*C) + c]     = s;
    part[(size_t)blockIdx.x * (2*C) + C + c] = ss;
  }
}

template<int C>
__global__ __launch_bounds__(256) void fin_kernel(const float* __restrict__ part,
                                                  const float* __restrict__ gv,
                                                  float* __restrict__ bn)
{
  int c = blockIdx.x, t = threadIdx.x;
  float s = 0.0f, ss = 0.0f;
  for (int b2 = t; b2 < 512; b2 += 256) {
    s  += part[(size_t)b2 * (2*C) + c];
    ss += part[(size_t)b2 * (2*C) + C + c];
  }
  __shared__ float ls[256], lss[256];
  ls[t] = s; lss[t] = ss;
  __syncthreads();
  for (int k = 128; k > 0; k >>= 1) {
    if (t < k) { ls[t] += ls[t+k]; lss[t] += lss[t+k]; }
    __syncthreads();
  }
  if (t == 0) {
    const float inv_n = 1.0f / 262144.0f;
    float mu  = ls[0] * inv_n;
    float var = fmaxf(lss[0] * inv_n - mu * mu, 0.0f);
    bn[c]     = mu;
    bn[C + c] = gv[c] / sqrtf(var + EPS_F);
  }
}

// ---------------------------------------------------------------- 5b. In-place BN2+GELU activation
__global__ __launch_bounds__(256) void act_kernel(float* __restrict__ h,
                                                  const float* __restrict__ bnp,
                                                  const float* __restrict__ btp)
{
  int p = blockIdx.x * 256 + threadIdx.x;
  float* row = h + (size_t)p * 64;
#pragma unroll
  for (int j = 0; j < 64; j += 4) {
    float4 v = *(const float4*)(row + j);
    v.x = gelu_f((v.x - bnp[j+0]) * bnp[64+j+0] + btp[j+0]);
    v.y = gelu_f((v.y - bnp[j+1]) * bnp[64+j+1] + btp[j+1]);
    v.z = gelu_f((v.z - bnp[j+2]) * bnp[64+j+2] + btp[j+2]);
    v.w = gelu_f((v.w - bnp[j+3]) * bnp[64+j+3] + btp[j+3]);
    *(float4*)(row + j) = v;
  }
}

// ---------------------------------------------------------------- 6. Layer-3 stats (32-ch chunks, register-resident; R10-verified)
__global__ __launch_bounds__(256, 1) void l3stats_kernel(
    const float* __restrict__ g2, const float* __restrict__ W3,
    const float* __restrict__ b3, float* __restrict__ part)
{
  int t = threadIdx.x;
  int gb = blockIdx.x >> 2, chunk = blockIdx.x & 3;
  int og0 = chunk * 32;
  int p = gb * 256 + t;
  const float* row = g2 + (size_t)p * 64;
  float in[64];
#pragma unroll
  for (int j = 0; j < 64; j += 4) {
    float4 v = *(const float4*)(row + j);
    in[j+0] = v.x; in[j+1] = v.y; in[j+2] = v.z; in[j+3] = v.w;
  }
  float s_[32], q_[32];
  for (int o4 = 0; o4 < 8; ++o4) {
    const float* w0 = W3 + (size_t)(og0 + o4 * 4) * 64;
    float a0 = b3[og0+o4*4+0], a1 = b3[og0+o4*4+1], a2 = b3[og0+o4*4+2], a3 = b3[og0+o4*4+3];
#pragma unroll
    for (int j = 0; j < 64; ++j) {
      float x = in[j];
      a0 = fmaf(x, w0[j],      a0);
      a1 = fmaf(x, w0[64+j],   a1);
      a2 = fmaf(x, w0[128+j],  a2);
      a3 = fmaf(x, w0[192+j],  a3);
    }
    int o = o4 * 4;
    s_[o]=a0; s_[o+1]=a1; s_[o+2]=a2; s_[o+3]=a3;
    q_[o]=a0*a0; q_[o+1]=a1*a1; q_[o+2]=a2*a2; q_[o+3]=a3*a3;
  }

  int wv = t >> 6, lane = t & 63;
  tree_step<1,16>(s_, q_, lane);
  tree_step<2, 8>(s_, q_, lane);
  tree_step<4, 4>(s_, q_, lane);
  tree_step<8, 2>(s_, q_, lane);
  tree_step<16,1>(s_, q_, lane);
  s_[0] += __shfl_xor(s_[0], 32, 64);
  q_[0] += __shfl_xor(q_[0], 32, 64);

  int ch = (int)(__brev((unsigned)(lane & 31)) >> 27);
  float* pw = part + ((size_t)blockIdx.x * 4 + wv) * 64;
  if (lane < 32) { pw[ch] = s_[0]; pw[32 + ch] = q_[0]; }
}

__global__ __launch_bounds__(256) void fin3_kernel(const float* __restrict__ part,
                                                   const float* __restrict__ gv,
                                                   float* __restrict__ bn)
{
  int c = blockIdx.x, t = threadIdx.x;
  int chunk = c >> 5, j = c & 31;
  float s = 0.0f, ss = 0.0f;
  for (int gb = t; gb < 1024; gb += 256) {
    int blk = gb * 4 + chunk;
#pragma unroll
    for (int wv = 0; wv < 4; ++wv) {
      const float* pw = part + ((size_t)blk * 4 + wv) * 64;
      s  += pw[j];
      ss += pw[32 + j];
    }
  }
  __shared__ float ls[256], lss[256];
  ls[t] = s; lss[t] = ss;
  __syncthreads();
  for (int k = 128; k > 0; k >>= 1) {
    if (t < k) { ls[t] += ls[t+k]; lss[t] += lss[t+k]; }
    __syncthreads();
  }
  if (t == 0) {
    const float inv_n = 1.0f / 262144.0f;
    float mu  = ls[0] * inv_n;
    float var = fmaxf(lss[0] * inv_n - mu * mu, 0.0f);
    bn[c]       = mu;
    bn[128 + c] = gv[c] / sqrtf(var + EPS_F);
  }
}

// ---------------------------------------------------------------- 7. Fused L3 GEMM + BN3 + GELU + maxpool (R10-verified 32-ch chunks)
__global__ __launch_bounds__(256, 1) void pool3_kernel(
    const float* __restrict__ g2, const float* __restrict__ W3,
    const float* __restrict__ b3,
    const float* __restrict__ bnp3,   // [mu3[128], a3[128]]
    const float* __restrict__ btp3,
    float* __restrict__ out1)
{
  int t = threadIdx.x;
  int gb = blockIdx.x >> 2, chunk = blockIdx.x & 3;
  int og0 = chunk * 32;
  int p = gb * 256 + t;
  const float* row = g2 + (size_t)p * 64;
  float in[64];
#pragma unroll
  for (int j = 0; j < 64; j += 4) {
    float4 v = *(const float4*)(row + j);
    in[j+0] = v.x; in[j+1] = v.y; in[j+2] = v.z; in[j+3] = v.w;
  }
  float g_[32];
  for (int o4 = 0; o4 < 8; ++o4) {
    const float* w0 = W3 + (size_t)(og0 + o4 * 4) * 64;
    float a0 = b3[og0+o4*4+0], a1 = b3[og0+o4*4+1], a2 = b3[og0+o4*4+2], a3 = b3[og0+o4*4+3];
#pragma unroll
    for (int j = 0; j < 64; ++j) {
      float x = in[j];
      a0 = fmaf(x, w0[j],      a0);
      a1 = fmaf(x, w0[64+j],   a1);
      a2 = fmaf(x, w0[128+j],  a2);
      a3 = fmaf(x, w0[192+j],  a3);
    }
    int oc0 = og0 + o4 * 4, o = o4 * 4;
    g_[o]   = gelu_f((a0 - bnp3[oc0+0]) * bnp3[128+oc0+0] + btp3[oc0+0]);
    g_[o+1] = gelu_f((a1 - bnp3[oc0+1]) * bnp3[128+oc0+1] + btp3[oc0+1]);
    g_[o+2] = gelu_f((a2 - bnp3[oc0+2]) * bnp3[128+oc0+2] + btp3[oc0+2]);
    g_[o+3] = gelu_f((a3 - bnp3[oc0+3]) * bnp3[128+oc0+3] + btp3[oc0+3]);
  }

  ptree_step<1,16>(g_, t);
  ptree_step<2, 8>(g_, t);
  ptree_step<4, 4>(g_, t);
  ptree_step<8, 2>(g_, t);
  ptree_step<16,1>(g_, t);

  int ch = (int)(__brev((unsigned)(t & 31)) >> 27);
  int gm = gb * 8 + (t >> 5);
  out1[(size_t)gm * 128 + og0 + ch] = g_[0];
}

// ---------------------------------------------------------------- diagnostic fill
__global__ void fill_kernel(float* __restrict__ out1) {
  out1[blockIdx.x * 256 + threadIdx.x] = 1.0e6f;
}

// ---------------------------------------------------------------- launch
extern "C" void kernel_launch(void* const* d_in, const int* in_sizes, int n_in,
                              void* d_out, int out_size, void* d_ws, size_t ws_size,
                              hipStream_t stream)
{
  (void)in_sizes; (void)n_in; (void)out_size;
  const float* xyz   = (const float*)d_in[0];
  const float* feats = (const float*)d_in[1];
  const float* W1  = (const float*)d_in[2];
  const float* b1  = (const float*)d_in[3];
  const float* g1  = (const float*)d_in[4];
  const float* bt1 = (const float*)d_in[5];
  const float* W2  = (const float*)d_in[6];
  const float* b2  = (const float*)d_in[7];
  const float* g2  = (const float*)d_in[8];
  const float* bt2 = (const float*)d_in[9];
  const float* W3  = (const float*)d_in[10];
  const float* b3  = (const float*)d_in[11];
  const float* g3  = (const float*)d_in[12];
  const float* bt3 = (const float*)d_in[13];

  float* out0 = (float*)d_out;
  float* out1 = out0 + (size_t)BATCH * MCENT * 3;

  char* ws = (char*)d_ws;
  int*   gidx    = (int*)(ws + 0);
  float* part    = (float*)(ws + (1u << 20));
  float* bn0     = (float*)(ws + 5u * (1u << 20));
  float* bn1     = bn0 + 128;
  float* bn2     = bn0 + 256;
  float* dist_ws = (float*)(ws + 5u * (1u << 20) + 65536u);
  float* cst     = (float*)(ws + 5u * (1u << 20) + 65536u + 262144u);
  float* h1      = (float*)(ws + 6u * (1u << 20));

  if (ws_size < WS_NEED) {
    fill_kernel<<<4096, 256, 0, stream>>>(out1);
    return;
  }

  // 19 dispatches: FPS phases 0..15; bq lags 1, l1 lags 2, L1-stats lags 3.
  for (int s0 = 0; s0 <= MCENT + 2 * FPS_STEPS; s0 += FPS_STEPS)
    mega_kernel<<<132, 512, 0, stream>>>(xyz, out0, dist_ws, cst, s0,
                                         gidx, feats, W1, b1, h1, part);

  fin_kernel<64><<<64, 256, 0, stream>>>(part, g1, bn0);
  l2_kernel<<<1024, 256, 0, stream>>>(h1, W2, b2, bn0, bt1);
  stats_kernel<64><<<512, 256, 0, stream>>>(h1, part);
  fin_kernel<64><<<64, 256, 0, stream>>>(part, g2, bn1);
  act_kernel<<<1024, 256, 0, stream>>>(h1, bn1, bt2);          // h1 -> gelu'd
  l3stats_kernel<<<4096, 256, 0, stream>>>(h1, W3, b3, part);
  fin3_kernel<<<128, 256, 0, stream>>>(part, g3, bn2);
  pool3_kernel<<<4096, 256, 0, stream>>>(h1, W3, b3, bn2, bt3, out1);
}

// Round 13
// 1504.610 us; speedup vs baseline: 1.4966x; 1.4966x over previous
//
#include <hip/hip_runtime.h>
#include <cstdint>
#include <cstddef>

#define BATCH 8
#define NPTS  8192
#define MCENT 1024
#define KNN   32
#define CFEAT 64
#define EPS_F 1e-5f

// Workspace layout (70 MiB):
//   gidx : [0, 1MiB)          part : [1MiB, 5MiB)
//   bn   : [5MiB, +2KiB)      fps dist : [5MiB+64KiB, +256KiB)  cst : after
//   h1   : [6MiB, 70MiB)      f32 [262144][64], reused in-place as h2
#define WS_NEED 73400320ull

// LESSONS (R9/R11/R12 regressions — do not retry):
//  * >~100 live floats/thread in the GEMM-reduce kernels spills (WRITE_SIZE
//    balloons): keep per-thread channel arrays <=32, don't keep in[64] live
//    across a chunk loop (R11: 130->503us).
//  * Two FPS batches sharing one __syncthreads are barrier-coupled — no
//    latency hiding, and global coord lookup on the serial chain adds ~400cy
//    (R12: mega 60->100us). Keep FPS: 1 batch/block, LDS pts table.

// ---------------------------------------------------------------- fast erf GELU
__device__ __forceinline__ float erf_fast(float x) {
  float a = fabsf(x);
  float t = __builtin_amdgcn_rcpf(fmaf(0.3275911f, a, 1.0f));
  float p = fmaf(1.061405429f, t, -1.453152027f);
  p = fmaf(p, t, 1.421413741f);
  p = fmaf(p, t, -0.284496736f);
  p = fmaf(p, t, 0.254829592f);
  float e = __expf(-a * a);
  float y = fmaf(-p * t, e, 1.0f);
  return copysignf(y, x);
}
__device__ __forceinline__ float gelu_f(float x) {
  return 0.5f * x * (1.0f + erf_fast(x * 0.70710678118654752440f));
}

// DPP wave64 reduce helpers.
template<int CTRL>
__device__ __forceinline__ float dpp_max_step(float v) {
  int s = __builtin_amdgcn_update_dpp(__float_as_int(v), __float_as_int(v),
                                      CTRL, 0xf, 0xf, false);
  return fmaxf(v, __int_as_float(s));
}
__device__ __forceinline__ float wave_max_dpp(float v) {
  v = dpp_max_step<0x111>(v);
  v = dpp_max_step<0x112>(v);
  v = dpp_max_step<0x114>(v);
  v = dpp_max_step<0x118>(v);
  v = dpp_max_step<0x142>(v);
  v = dpp_max_step<0x143>(v);
  return v;                    // lane 63 = wave max
}
template<int CTRL>
__device__ __forceinline__ unsigned long long dpp_min64_step(unsigned long long v) {
  int lo = __builtin_amdgcn_update_dpp((int)(unsigned)(v & 0xffffffffull),
                                       (int)(unsigned)(v & 0xffffffffull),
                                       CTRL, 0xf, 0xf, false);
  int hi = __builtin_amdgcn_update_dpp((int)(unsigned)(v >> 32),
                                       (int)(unsigned)(v >> 32),
                                       CTRL, 0xf, 0xf, false);
  unsigned long long o = (((unsigned long long)(unsigned)hi) << 32) | (unsigned)lo;
  return o < v ? o : v;
}
__device__ __forceinline__ unsigned long long wave_min64_dpp(unsigned long long v) {
  v = dpp_min64_step<0x111>(v);
  v = dpp_min64_step<0x112>(v);
  v = dpp_min64_step<0x114>(v);
  v = dpp_min64_step<0x118>(v);
  v = dpp_min64_step<0x142>(v);
  v = dpp_min64_step<0x143>(v);
  return v;                    // lane 63 = wave min
}

// Channel-exchange tree steps, COMPILE-TIME bounds (rule #20).
template<int M, int HALF>
__device__ __forceinline__ void tree_step(float* s_, float* q_, int lane) {
  bool up = (lane & M) != 0;
#pragma unroll
  for (int j = 0; j < HALF; ++j) {
    float ks = up ? s_[j+HALF] : s_[j];
    float ds = up ? s_[j]      : s_[j+HALF];
    s_[j] = ks + __shfl_xor(ds, M, 64);
    float kq = up ? q_[j+HALF] : q_[j];
    float dq = up ? q_[j]      : q_[j+HALF];
    q_[j] = kq + __shfl_xor(dq, M, 64);
  }
}
template<int M, int HALF>
__device__ __forceinline__ void ptree_step(float* g_, int kbit) {
  bool up = (kbit & M) != 0;
#pragma unroll
  for (int j = 0; j < HALF; ++j) {
    float kv = up ? g_[j+HALF] : g_[j];
    float dv = up ? g_[j]      : g_[j+HALF];
    g_[j] = fmaxf(kv, __shfl_xor(dv, M, 64));
  }
}

// ---------------------------------------------------------------- 1. MEGA kernel
// One dispatch per 64-step FPS phase; role-split blocks use idle CUs:
//   blk 0-7    : FPS phase s0                (8 CUs)
//   blk 8-71   : ball query, phase s0-64     (prev dispatch's centroids)
//   blk 72-103 : layer-1,   phase s0-128
//   blk 104-135: L1 BN stats, phase s0-192   (rows written prev dispatch)
// Same-stream dispatch ordering guarantees producer visibility.
#define FPS_STEPS 64
#define BQCAP 512
__global__ __launch_bounds__(512, 1) void mega_kernel(
    const float* __restrict__ xyz, float* __restrict__ new_xyz,
    float* __restrict__ dist_ws, float* __restrict__ cst, int s0,
    int* __restrict__ gidx, const float* __restrict__ feats,
    const float* __restrict__ W1, const float* __restrict__ b1v,
    float* __restrict__ h1, float* __restrict__ part)
{
  __shared__ float pts[NPTS * 3];                  // 96 KiB (fps)
  __shared__ float outb[FPS_STEPS * 3];
  __shared__ unsigned long long keys[2][8];
  __shared__ unsigned long long list[8][BQCAP];    // 32 KiB (bq)
  __shared__ float ls[512], lss[512];              // 4 KiB (stats)
  int blk = blockIdx.x, t = threadIdx.x;

  if (blk < 8) {
    // ---------------- FPS role (verified bit-exact jnp arithmetic) ----------
    if (s0 >= MCENT) return;
    int b = blk;
    const float* xb = xyz + (size_t)b * NPTS * 3;
    float px[16], py[16], pz[16], dist[16];
    {
      const float4* src = (const float4*)(xb + (size_t)t * 48);
      float4 buf[12];
#pragma unroll
      for (int i = 0; i < 12; ++i) buf[i] = src[i];
      const float* f = (const float*)buf;
#pragma unroll
      for (int i = 0; i < 16; ++i) {
        px[i] = f[i*3+0]; py[i] = f[i*3+1]; pz[i] = f[i*3+2];
      }
      float4* dst = (float4*)(pts + (size_t)t * 48);
#pragma unroll
      for (int i = 0; i < 12; ++i) dst[i] = buf[i];
    }
    float* dw = dist_ws + (size_t)b * NPTS + (size_t)t * 16;
    float cx, cy, cz;
    if (s0 == 0) {
#pragma unroll
      for (int i = 0; i < 16; ++i) dist[i] = __builtin_inff();
      cx = xb[0]; cy = xb[1]; cz = xb[2];
    } else {
      float4 d0 = *(const float4*)(dw + 0);
      float4 d1 = *(const float4*)(dw + 4);
      float4 d2 = *(const float4*)(dw + 8);
      float4 d3 = *(const float4*)(dw + 12);
      dist[0]=d0.x; dist[1]=d0.y; dist[2]=d0.z; dist[3]=d0.w;
      dist[4]=d1.x; dist[5]=d1.y; dist[6]=d1.z; dist[7]=d1.w;
      dist[8]=d2.x; dist[9]=d2.y; dist[10]=d2.z; dist[11]=d2.w;
      dist[12]=d3.x; dist[13]=d3.y; dist[14]=d3.z; dist[15]=d3.w;
      cx = cst[b*3+0]; cy = cst[b*3+1]; cz = cst[b*3+2];
    }
    int lane = t & 63, wv = t >> 6;

    for (int s = 0; s < FPS_STEPS; ++s) {
      if (t == 0) { outb[s*3+0] = cx; outb[s*3+1] = cy; outb[s*3+2] = cz; }
      float bd = -1.0f; int bslot = 0;
#pragma unroll
      for (int i = 0; i < 16; ++i) {
        float dx = __fsub_rn(px[i], cx);
        float dy = __fsub_rn(py[i], cy);
        float dz = __fsub_rn(pz[i], cz);
        float d  = __fadd_rn(__fadd_rn(__fmul_rn(dx,dx), __fmul_rn(dy,dy)), __fmul_rn(dz,dz));
        float nd = fminf(dist[i], d);
        dist[i] = nd;
        if (nd > bd) { bd = nd; bslot = i; }    // strict >: first max in idx order
      }
      float w = wave_max_dpp(bd);
      float wmax = __int_as_float(__builtin_amdgcn_readlane(__float_as_int(w), 63));
      unsigned long long mk = __ballot(bd == wmax);
      int sl = __ffsll((long long)mk) - 1;      // lowest lane = lowest idx
      int widx = __builtin_amdgcn_readlane(t * 16 + bslot, sl);
      if (lane == 0)
        keys[s & 1][wv] = (((unsigned long long)__float_as_uint(wmax)) << 32)
                          | (unsigned)(8191 - widx);
      __syncthreads();
      unsigned long long bk = keys[s & 1][0];
#pragma unroll
      for (int w2 = 1; w2 < 8; ++w2) {
        unsigned long long o = keys[s & 1][w2];
        if (o > bk) bk = o;
      }
      int idx = 8191 - (int)(unsigned)(bk & 0xffffffffull);
      cx = pts[idx*3+0]; cy = pts[idx*3+1]; cz = pts[idx*3+2];
    }

    *(float4*)(dw + 0)  = make_float4(dist[0], dist[1], dist[2], dist[3]);
    *(float4*)(dw + 4)  = make_float4(dist[4], dist[5], dist[6], dist[7]);
    *(float4*)(dw + 8)  = make_float4(dist[8], dist[9], dist[10], dist[11]);
    *(float4*)(dw + 12) = make_float4(dist[12], dist[13], dist[14], dist[15]);
    if (t == 0) { cst[b*3+0] = cx; cst[b*3+1] = cy; cst[b*3+2] = cz; }
    __syncthreads();
    float* ob = new_xyz + (size_t)b * MCENT * 3 + (size_t)s0 * 3;
    for (int i = t; i < FPS_STEPS * 3; i += 512) ob[i] = outb[i];

  } else if (blk < 72) {
    // ---------------- Ball-query role: phase s0-64 --------------------------
    int ph = s0 - FPS_STEPS;
    if (ph < 0 || ph >= MCENT) return;
    int wv = t >> 6, lane = t & 63;
    int c  = (blk - 8) * 8 + wv;                 // 0..511
    int b  = c >> 6;
    int ci = ph + (c & 63);
    int gm = b * MCENT + ci;
    const float* cc = new_xyz + (size_t)gm * 3;
    float c0 = cc[0], c1 = cc[1], c2 = cc[2];
    float sc = __fadd_rn(__fadd_rn(__fmul_rn(c0,c0), __fmul_rn(c1,c1)), __fmul_rn(c2,c2));
    const float* xb = xyz + (size_t)b * NPTS * 3;

    unsigned cnt = 0;
    for (int j0 = 0; j0 < NPTS; j0 += 64) {
      int j = j0 + lane;
      float x = xb[j*3+0], y = xb[j*3+1], z = xb[j*3+2];
      float sx  = __fadd_rn(__fadd_rn(__fmul_rn(x,x), __fmul_rn(y,y)), __fmul_rn(z,z));
      float dot = __fadd_rn(__fadd_rn(__fmul_rn(c0,x), __fmul_rn(c1,y)), __fmul_rn(c2,z));
      float d2  = __fsub_rn(__fadd_rn(sc, sx), __fmul_rn(2.0f, dot));
      float dist = sqrtf(fmaxf(d2, 0.0f));
      bool in_ = (dist <= 0.5f);
      unsigned long long mask = __ballot(in_);
      unsigned off = (unsigned)__popcll(mask & ((1ull << lane) - 1ull));
      if (in_) {
        unsigned pos = cnt + off;
        if (pos < BQCAP)
          list[wv][pos] = (((unsigned long long)__float_as_uint(dist)) << 32) | (unsigned)j;
      }
      cnt += (unsigned)__popcll(mask);
    }
    if (cnt > BQCAP) cnt = BQCAP;

    unsigned long long e[8];
#pragma unroll
    for (int i = 0; i < 8; ++i) {
      unsigned pos = (unsigned)lane + ((unsigned)i << 6);
      e[i] = (pos < cnt) ? list[wv][pos] : ~0ull;
    }
#define CE_(a_, b_) { bool sw = e[b_] < e[a_]; \
                      unsigned long long lo_ = sw ? e[b_] : e[a_]; \
                      unsigned long long hi_ = sw ? e[a_] : e[b_]; \
                      e[a_] = lo_; e[b_] = hi_; }
    CE_(0,1) CE_(2,3) CE_(4,5) CE_(6,7)
    CE_(0,2) CE_(1,3) CE_(4,6) CE_(5,7)
    CE_(1,2) CE_(5,6)
    CE_(0,4) CE_(1,5) CE_(2,6) CE_(3,7)
    CE_(2,4) CE_(3,5)
    CE_(1,2) CE_(3,4) CE_(5,6)
#undef CE_

    int* gout = gidx + (size_t)gm * KNN;
    int first = 0;
    int kmax = (cnt < (unsigned)KNN) ? (int)cnt : KNN;
    for (int k = 0; k < KNN; ++k) {
      if (k < kmax) {
        unsigned long long wr = wave_min64_dpp(e[0]);
        unsigned lo32 = (unsigned)__builtin_amdgcn_readlane((int)(unsigned)(wr & 0xffffffffull), 63);
        unsigned hi32 = (unsigned)__builtin_amdgcn_readlane((int)(unsigned)(wr >> 32), 63);
        unsigned long long wmin = (((unsigned long long)hi32) << 32) | lo32;
        int idxv = (int)lo32;
        if (k == 0) first = idxv;
        if (lane == 0) gout[k] = idxv;
        bool win = (e[0] == wmin);
#pragma unroll
        for (int i = 0; i < 7; ++i) e[i] = win ? e[i+1] : e[i];
        e[7] = win ? ~0ull : e[7];
      } else {
        if (lane == 0) gout[k] = first;
      }
    }

  } else if (blk < 104) {
    // ---------------- Layer-1 role: phase s0-128 ----------------------------
    int ph = s0 - 2 * FPS_STEPS;
    if (ph < 0 || ph >= MCENT) return;
    int row = (blk - 72) * 512 + t;              // 0..16383
    int c   = row >> 5;                          // centroid seq 0..511
    int k   = row & 31;
    int b   = c >> 6;
    int ci  = ph + (c & 63);
    int p   = b * (MCENT * KNN) + ci * KNN + k;  // global h1 row
    int idx = gidx[p];
    const float* cc = new_xyz + (size_t)(b * MCENT + ci) * 3;
    const float* q  = xyz + (size_t)(b * NPTS + idx) * 3;
    float in[67];
    in[0] = q[0] - cc[0];
    in[1] = q[1] - cc[1];
    in[2] = q[2] - cc[2];
    const float* fr = feats + (size_t)(b * NPTS + idx) * CFEAT;
#pragma unroll
    for (int j = 0; j < 64; j += 4) {
      float4 v = *(const float4*)(fr + j);
      in[3+j] = v.x; in[4+j] = v.y; in[5+j] = v.z; in[6+j] = v.w;
    }
    float* orow = h1 + (size_t)p * 64;
    for (int o4 = 0; o4 < 16; ++o4) {
      const float* w0 = W1 + (size_t)(o4 * 4) * 67;
      float a0 = b1v[o4*4+0], a1 = b1v[o4*4+1], a2 = b1v[o4*4+2], a3 = b1v[o4*4+3];
#pragma unroll
      for (int j = 0; j < 67; ++j) {
        float x = in[j];
        a0 = fmaf(x, w0[j],       a0);
        a1 = fmaf(x, w0[67+j],    a1);
        a2 = fmaf(x, w0[134+j],   a2);
        a3 = fmaf(x, w0[201+j],   a3);
      }
      *(float4*)(orow + o4*4) = make_float4(a0, a1, a2, a3);
    }

  } else {
    // ---------------- L1 BN-stats role: phase s0-192 ------------------------
    int ph = s0 - 3 * FPS_STEPS;
    if (ph < 0 || ph >= MCENT) return;
    int sb = blk - 104;                          // 0..31
    int b  = sb >> 2;
    int rb = (sb & 3) * 512;
    int c  = t & 63, g = t >> 6;                 // 8 groups of 64
    size_t base = (size_t)b * (MCENT * KNN) + (size_t)ph * KNN + rb;
    float s = 0.0f, ss = 0.0f;
    for (int r = g; r < 512; r += 8) {
      float v = h1[(base + r) * 64 + c];
      s += v;
      ss = fmaf(v, v, ss);
    }
    ls[t] = s; lss[t] = ss;
    __syncthreads();
    if (g == 0) {
#pragma unroll
      for (int gg = 1; gg < 8; ++gg) { s += ls[gg*64 + c]; ss += lss[gg*64 + c]; }
      int pblk = (ph >> 6) * 32 + sb;            // 0..511
      part[(size_t)pblk * 128 + c]      = s;
      part[(size_t)pblk * 128 + 64 + c] = ss;
    }
  }
}

// ---------------------------------------------------------------- 4. Layer 2: BN1+GELU then W2, IN-PLACE
__global__ __launch_bounds__(256) void l2_kernel(
    float* __restrict__ h, const float* __restrict__ W,
    const float* __restrict__ bv, const float* __restrict__ bnp,
    const float* __restrict__ btp)
{
  int p = blockIdx.x * 256 + threadIdx.x;
  float* row = h + (size_t)p * 64;
  float in[64];
#pragma unroll
  for (int j = 0; j < 64; j += 4) {
    float4 v = *(const float4*)(row + j);
    in[j+0] = gelu_f((v.x - bnp[j+0]) * bnp[64+j+0] + btp[j+0]);
    in[j+1] = gelu_f((v.y - bnp[j+1]) * bnp[64+j+1] + btp[j+1]);
    in[j+2] = gelu_f((v.z - bnp[j+2]) * bnp[64+j+2] + btp[j+2]);
    in[j+3] = gelu_f((v.w - bnp[j+3]) * bnp[64+j+3] + btp[j+3]);
  }
  for (int o4 = 0; o4 < 16; ++o4) {
    const float* w0 = W + (size_t)(o4 * 4) * 64;
    float a0 = bv[o4*4+0], a1 = bv[o4*4+1], a2 = bv[o4*4+2], a3 = bv[o4*4+3];
#pragma unroll
    for (int j = 0; j < 64; ++j) {
      float x = in[j];
      a0 = fmaf(x, w0[j],      a0);
      a1 = fmaf(x, w0[64+j],   a1);
      a2 = fmaf(x, w0[128+j],  a2);
      a3 = fmaf(x, w0[192+j],  a3);
    }
    *(float4*)(row + o4*4) = make_float4(a0, a1, a2, a3);
  }
}

// ---------------------------------------------------------------- 5. Deterministic BN stats (layer 2)
template<int C>
__global__ __launch_bounds__(256) void stats_kernel(const float* __restrict__ h,
                                                    float* __restrict__ part)
{
  constexpr int G = 256 / C;
  int t = threadIdx.x;
  int c = t % C, g = t / C;
  const float* base = h + (size_t)blockIdx.x * 512 * C;
  float s = 0.0f, ss = 0.0f;
  for (int r = g; r < 512; r += G) {
    float v = base[(size_t)r * C + c];
    s += v;
    ss = fmaf(v, v, ss);
  }
  __shared__ float ls[256], lss[256];
  ls[t] = s; lss[t] = ss;
  __syncthreads();
  if (g == 0) {
    for (int gg = 1; gg < G; ++gg) { s += ls[gg*C + c]; ss += lss[gg*C + c]; }
    part[(size_t)blockIdx.x * (2*C) + c]     = s;
    part[(size_t)blockIdx.x * (2*C) + C + c] = ss;
  }
}

template<int C>
__global__ __launch_bounds__(256) void fin_kernel(const float* __restrict__ part,
                                                  const float* __restrict__ gv,
                                                  float* __restrict__ bn)
{
  int c = blockIdx.x, t = threadIdx.x;
  float s = 0.0f, ss = 0.0f;
  for (int b2 = t; b2 < 512; b2 += 256) {
    s  += part[(size_t)b2 * (2*C) + c];
    ss += part[(size_t)b2 * (2*C) + C + c];
  }
  __shared__ float ls[256], lss[256];
  ls[t] = s; lss[t] = ss;
  __syncthreads();
  for (int k = 128; k > 0; k >>= 1) {
    if (t < k) { ls[t] += ls[t+k]; lss[t] += lss[t+k]; }
    __syncthreads();
  }
  if (t == 0) {
    const float inv_n = 1.0f / 262144.0f;
    float mu  = ls[0] * inv_n;
    float var = fmaxf(lss[0] * inv_n - mu * mu, 0.0f);
    bn[c]     = mu;
    bn[C + c] = gv[c] / sqrtf(var + EPS_F);
  }
}

// ---------------------------------------------------------------- 5b. In-place BN2+GELU activation
__global__ __launch_bounds__(256) void act_kernel(float* __restrict__ h,
                                                  const float* __restrict__ bnp,
                                                  const float* __restrict__ btp)
{
  int p = blockIdx.x * 256 + threadIdx.x;
  float* row = h + (size_t)p * 64;
#pragma unroll
  for (int j = 0; j < 64; j += 4) {
    float4 v = *(const float4*)(row + j);
    v.x = gelu_f((v.x - bnp[j+0]) * bnp[64+j+0] + btp[j+0]);
    v.y = gelu_f((v.y - bnp[j+1]) * bnp[64+j+1] + btp[j+1]);
    v.z = gelu_f((v.z - bnp[j+2]) * bnp[64+j+2] + btp[j+2]);
    v.w = gelu_f((v.w - bnp[j+3]) * bnp[64+j+3] + btp[j+3]);
    *(float4*)(row + j) = v;
  }
}

// ---------------------------------------------------------------- 6. Layer-3 stats (32-ch chunks, register-resident; R10-verified)
__global__ __launch_bounds__(256, 1) void l3stats_kernel(
    const float* __restrict__ g2, const float* __restrict__ W3,
    const float* __restrict__ b3, float* __restrict__ part)
{
  int t = threadIdx.x;
  int gb = blockIdx.x >> 2, chunk = blockIdx.x & 3;
  int og0 = chunk * 32;
  int p = gb * 256 + t;
  const float* row = g2 + (size_t)p * 64;
  float in[64];
#pragma unroll
  for (int j = 0; j < 64; j += 4) {
    float4 v = *(const float4*)(row + j);
    in[j+0] = v.x; in[j+1] = v.y; in[j+2] = v.z; in[j+3] = v.w;
  }
  float s_[32], q_[32];
  for (int o4 = 0; o4 < 8; ++o4) {
    const float* w0 = W3 + (size_t)(og0 + o4 * 4) * 64;
    float a0 = b3[og0+o4*4+0], a1 = b3[og0+o4*4+1], a2 = b3[og0+o4*4+2], a3 = b3[og0+o4*4+3];
#pragma unroll
    for (int j = 0; j < 64; ++j) {
      float x = in[j];
      a0 = fmaf(x, w0[j],      a0);
      a1 = fmaf(x, w0[64+j],   a1);
      a2 = fmaf(x, w0[128+j],  a2);
      a3 = fmaf(x, w0[192+j],  a3);
    }
    int o = o4 * 4;
    s_[o]=a0; s_[o+1]=a1; s_[o+2]=a2; s_[o+3]=a3;
    q_[o]=a0*a0; q_[o+1]=a1*a1; q_[o+2]=a2*a2; q_[o+3]=a3*a3;
  }

  int wv = t >> 6, lane = t & 63;
  tree_step<1,16>(s_, q_, lane);
  tree_step<2, 8>(s_, q_, lane);
  tree_step<4, 4>(s_, q_, lane);
  tree_step<8, 2>(s_, q_, lane);
  tree_step<16,1>(s_, q_, lane);
  s_[0] += __shfl_xor(s_[0], 32, 64);
  q_[0] += __shfl_xor(q_[0], 32, 64);

  int ch = (int)(__brev((unsigned)(lane & 31)) >> 27);
  float* pw = part + ((size_t)blockIdx.x * 4 + wv) * 64;
  if (lane < 32) { pw[ch] = s_[0]; pw[32 + ch] = q_[0]; }
}

__global__ __launch_bounds__(256) void fin3_kernel(const float* __restrict__ part,
                                                   const float* __restrict__ gv,
                                                   float* __restrict__ bn)
{
  int c = blockIdx.x, t = threadIdx.x;
  int chunk = c >> 5, j = c & 31;
  float s = 0.0f, ss = 0.0f;
  for (int gb = t; gb < 1024; gb += 256) {
    int blk = gb * 4 + chunk;
#pragma unroll
    for (int wv = 0; wv < 4; ++wv) {
      const float* pw = part + ((size_t)blk * 4 + wv) * 64;
      s  += pw[j];
      ss += pw[32 + j];
    }
  }
  __shared__ float ls[256], lss[256];
  ls[t] = s; lss[t] = ss;
  __syncthreads();
  for (int k = 128; k > 0; k >>= 1) {
    if (t < k) { ls[t] += ls[t+k]; lss[t] += lss[t+k]; }
    __syncthreads();
  }
  if (t == 0) {
    const float inv_n = 1.0f / 262144.0f;
    float mu  = ls[0] * inv_n;
    float var = fmaxf(lss[0] * inv_n - mu * mu, 0.0f);
    bn[c]       = mu;
    bn[128 + c] = gv[c] / sqrtf(var + EPS_F);
  }
}

// ---------------------------------------------------------------- 7. Fused L3 GEMM + BN3 + GELU + maxpool (R10-verified 32-ch chunks)
__global__ __launch_bounds__(256, 1) void pool3_kernel(
    const float* __restrict__ g2, const float* __restrict__ W3,
    const float* __restrict__ b3,
    const float* __restrict__ bnp3,   // [mu3[128], a3[128]]
    const float* __restrict__ btp3,
    float* __restrict__ out1)
{
  int t = threadIdx.x;
  int gb = blockIdx.x >> 2, chunk = blockIdx.x & 3;
  int og0 = chunk * 32;
  int p = gb * 256 + t;
  const float* row = g2 + (size_t)p * 64;
  float in[64];
#pragma unroll
  for (int j = 0; j < 64; j += 4) {
    float4 v = *(const float4*)(row + j);
    in[j+0] = v.x; in[j+1] = v.y; in[j+2] = v.z; in[j+3] = v.w;
  }
  float g_[32];
  for (int o4 = 0; o4 < 8; ++o4) {
    const float* w0 = W3 + (size_t)(og0 + o4 * 4) * 64;
    float a0 = b3[og0+o4*4+0], a1 = b3[og0+o4*4+1], a2 = b3[og0+o4*4+2], a3 = b3[og0+o4*4+3];
#pragma unroll
    for (int j = 0; j < 64; ++j) {
      float x = in[j];
      a0 = fmaf(x, w0[j],      a0);
      a1 = fmaf(x, w0[64+j],   a1);
      a2 = fmaf(x, w0[128+j],  a2);
      a3 = fmaf(x, w0[192+j],  a3);
    }
    int oc0 = og0 + o4 * 4, o = o4 * 4;
    g_[o]   = gelu_f((a0 - bnp3[oc0+0]) * bnp3[128+oc0+0] + btp3[oc0+0]);
    g_[o+1] = gelu_f((a1 - bnp3[oc0+1]) * bnp3[128+oc0+1] + btp3[oc0+1]);
    g_[o+2] = gelu_f((a2 - bnp3[oc0+2]) * bnp3[128+oc0+2] + btp3[oc0+2]);
    g_[o+3] = gelu_f((a3 - bnp3[oc0+3]) * bnp3[128+oc0+3] + btp3[oc0+3]);
  }

  ptree_step<1,16>(g_, t);
  ptree_step<2, 8>(g_, t);
  ptree_step<4, 4>(g_, t);
  ptree_step<8, 2>(g_, t);
  ptree_step<16,1>(g_, t);

  int ch = (int)(__brev((unsigned)(t & 31)) >> 27);
  int gm = gb * 8 + (t >> 5);
  out1[(size_t)gm * 128 + og0 + ch] = g_[0];
}

// ---------------------------------------------------------------- diagnostic fill
__global__ void fill_kernel(float* __restrict__ out1) {
  out1[blockIdx.x * 256 + threadIdx.x] = 1.0e6f;
}

// ---------------------------------------------------------------- launch
extern "C" void kernel_launch(void* const* d_in, const int* in_sizes, int n_in,
                              void* d_out, int out_size, void* d_ws, size_t ws_size,
                              hipStream_t stream)
{
  (void)in_sizes; (void)n_in; (void)out_size;
  const float* xyz   = (const float*)d_in[0];
  const float* feats = (const float*)d_in[1];
  const float* W1  = (const float*)d_in[2];
  const float* b1  = (const float*)d_in[3];
  const float* g1  = (const float*)d_in[4];
  const float* bt1 = (const float*)d_in[5];
  const float* W2  = (const float*)d_in[6];
  const float* b2  = (const float*)d_in[7];
  const float* g2  = (const float*)d_in[8];
  const float* bt2 = (const float*)d_in[9];
  const float* W3  = (const float*)d_in[10];
  const float* b3  = (const float*)d_in[11];
  const float* g3  = (const float*)d_in[12];
  const float* bt3 = (const float*)d_in[13];

  float* out0 = (float*)d_out;
  float* out1 = out0 + (size_t)BATCH * MCENT * 3;

  char* ws = (char*)d_ws;
  int*   gidx    = (int*)(ws + 0);
  float* part    = (float*)(ws + (1u << 20));
  float* bn0     = (float*)(ws + 5u * (1u << 20));
  float* bn1     = bn0 + 128;
  float* bn2     = bn0 + 256;
  float* dist_ws = (float*)(ws + 5u * (1u << 20) + 65536u);
  float* cst     = (float*)(ws + 5u * (1u << 20) + 65536u + 262144u);
  float* h1      = (float*)(ws + 6u * (1u << 20));

  if (ws_size < WS_NEED) {
    fill_kernel<<<4096, 256, 0, stream>>>(out1);
    return;
  }

  // 19 dispatches: FPS phases 0..15; bq lags 1, l1 lags 2, L1-stats lags 3.
  for (int s0 = 0; s0 <= MCENT + 2 * FPS_STEPS; s0 += FPS_STEPS)
    mega_kernel<<<136, 512, 0, stream>>>(xyz, out0, dist_ws, cst, s0,
                                         gidx, feats, W1, b1, h1, part);

  fin_kernel<64><<<64, 256, 0, stream>>>(part, g1, bn0);
  l2_kernel<<<1024, 256, 0, stream>>>(h1, W2, b2, bn0, bt1);
  stats_kernel<64><<<512, 256, 0, stream>>>(h1, part);
  fin_kernel<64><<<64, 256, 0, stream>>>(part, g2, bn1);
  act_kernel<<<1024, 256, 0, stream>>>(h1, bn1, bt2);          // h1 -> gelu'd
  l3stats_kernel<<<4096, 256, 0, stream>>>(h1, W3, b3, part);
  fin3_kernel<<<128, 256, 0, stream>>>(part, g3, bn2);
  pool3_kernel<<<4096, 256, 0, stream>>>(h1, W3, b3, bn2, bt3, out1);
}

// Round 14
// 1416.091 us; speedup vs baseline: 1.5902x; 1.0625x over previous
//
#include <hip/hip_runtime.h>
#include <hip/hip_fp16.h>
#include <cstdint>
#include <cstddef>

#define BATCH 8
#define NPTS  8192
#define MCENT 1024
#define KNN   32
#define CFEAT 64
#define EPS_F 1e-5f

// Workspace layout:
//   gidx : [0, 1MiB)          part : [1MiB, 5MiB)
//   bn   : [5MiB, +2KiB)      fps dist : [5MiB+64KiB, +256KiB)  cst : after
//   h1   : [6MiB, 70MiB)      f32 [262144][64]
//   h3t  : [70MiB, 134MiB)    f16 [8192][128][32]  (big-ws path only)
#define WS_NEED_SMALL 73400320ull
#define WS_NEED_BIG   140509184ull

// LESSONS (R9/R11/R12 regressions — do not retry):
//  * >~100 live floats/thread in the GEMM-reduce kernels spills / tanks
//    occupancy: channel arrays <=32, never keep in[64] live across a chunk
//    loop (R11: pool3 130->503us).
//  * Two FPS batches sharing one __syncthreads are barrier-coupled — no
//    latency hiding; global coord lookup on the serial chain adds ~400cy
//    (R12: mega 60->100us). Keep FPS: 1 batch/block, LDS pts table.

// ---------------------------------------------------------------- fast erf GELU
__device__ __forceinline__ float erf_fast(float x) {
  float a = fabsf(x);
  float t = __builtin_amdgcn_rcpf(fmaf(0.3275911f, a, 1.0f));
  float p = fmaf(1.061405429f, t, -1.453152027f);
  p = fmaf(p, t, 1.421413741f);
  p = fmaf(p, t, -0.284496736f);
  p = fmaf(p, t, 0.254829592f);
  float e = __expf(-a * a);
  float y = fmaf(-p * t, e, 1.0f);
  return copysignf(y, x);
}
__device__ __forceinline__ float gelu_f(float x) {
  return 0.5f * x * (1.0f + erf_fast(x * 0.70710678118654752440f));
}

// DPP wave64 reduce helpers.
template<int CTRL>
__device__ __forceinline__ float dpp_max_step(float v) {
  int s = __builtin_amdgcn_update_dpp(__float_as_int(v), __float_as_int(v),
                                      CTRL, 0xf, 0xf, false);
  return fmaxf(v, __int_as_float(s));
}
__device__ __forceinline__ float wave_max_dpp(float v) {
  v = dpp_max_step<0x111>(v);
  v = dpp_max_step<0x112>(v);
  v = dpp_max_step<0x114>(v);
  v = dpp_max_step<0x118>(v);
  v = dpp_max_step<0x142>(v);
  v = dpp_max_step<0x143>(v);
  return v;                    // lane 63 = wave max
}
template<int CTRL>
__device__ __forceinline__ unsigned long long dpp_min64_step(unsigned long long v) {
  int lo = __builtin_amdgcn_update_dpp((int)(unsigned)(v & 0xffffffffull),
                                       (int)(unsigned)(v & 0xffffffffull),
                                       CTRL, 0xf, 0xf, false);
  int hi = __builtin_amdgcn_update_dpp((int)(unsigned)(v >> 32),
                                       (int)(unsigned)(v >> 32),
                                       CTRL, 0xf, 0xf, false);
  unsigned long long o = (((unsigned long long)(unsigned)hi) << 32) | (unsigned)lo;
  return o < v ? o : v;
}
__device__ __forceinline__ unsigned long long wave_min64_dpp(unsigned long long v) {
  v = dpp_min64_step<0x111>(v);
  v = dpp_min64_step<0x112>(v);
  v = dpp_min64_step<0x114>(v);
  v = dpp_min64_step<0x118>(v);
  v = dpp_min64_step<0x142>(v);
  v = dpp_min64_step<0x143>(v);
  return v;                    // lane 63 = wave min
}

// Channel-exchange tree steps, COMPILE-TIME bounds (rule #20).
template<int M, int HALF>
__device__ __forceinline__ void tree_step(float* s_, float* q_, int lane) {
  bool up = (lane & M) != 0;
#pragma unroll
  for (int j = 0; j < HALF; ++j) {
    float ks = up ? s_[j+HALF] : s_[j];
    float ds = up ? s_[j]      : s_[j+HALF];
    s_[j] = ks + __shfl_xor(ds, M, 64);
    float kq = up ? q_[j+HALF] : q_[j];
    float dq = up ? q_[j]      : q_[j+HALF];
    q_[j] = kq + __shfl_xor(dq, M, 64);
  }
}
template<int M, int HALF>
__device__ __forceinline__ void ptree_step(float* g_, int kbit) {
  bool up = (kbit & M) != 0;
#pragma unroll
  for (int j = 0; j < HALF; ++j) {
    float kv = up ? g_[j+HALF] : g_[j];
    float dv = up ? g_[j]      : g_[j+HALF];
    g_[j] = fmaxf(kv, __shfl_xor(dv, M, 64));
  }
}

// ---------------------------------------------------------------- 1. MEGA kernel
// One dispatch per 64-step FPS phase; role-split blocks use idle CUs:
//   blk 0-7    : FPS phase s0                (8 CUs)
//   blk 8-71   : ball query, phase s0-64     (prev dispatch's centroids)
//   blk 72-103 : layer-1,   phase s0-128
//   blk 104-135: L1 BN stats, phase s0-192   (rows written prev dispatch)
// Same-stream dispatch ordering guarantees producer visibility.
#define FPS_STEPS 64
#define BQCAP 512
__global__ __launch_bounds__(512, 1) void mega_kernel(
    const float* __restrict__ xyz, float* __restrict__ new_xyz,
    float* __restrict__ dist_ws, float* __restrict__ cst, int s0,
    int* __restrict__ gidx, const float* __restrict__ feats,
    const float* __restrict__ W1, const float* __restrict__ b1v,
    float* __restrict__ h1, float* __restrict__ part)
{
  __shared__ float pts[NPTS * 3];                  // 96 KiB (fps)
  __shared__ float outb[FPS_STEPS * 3];
  __shared__ unsigned long long keys[2][8];
  __shared__ unsigned long long list[8][BQCAP];    // 32 KiB (bq)
  __shared__ float ls[512], lss[512];              // 4 KiB (stats)
  int blk = blockIdx.x, t = threadIdx.x;

  if (blk < 8) {
    // ---------------- FPS role (verified bit-exact jnp arithmetic) ----------
    if (s0 >= MCENT) return;
    int b = blk;
    const float* xb = xyz + (size_t)b * NPTS * 3;
    float px[16], py[16], pz[16], dist[16];
    {
      const float4* src = (const float4*)(xb + (size_t)t * 48);
      float4 buf[12];
#pragma unroll
      for (int i = 0; i < 12; ++i) buf[i] = src[i];
      const float* f = (const float*)buf;
#pragma unroll
      for (int i = 0; i < 16; ++i) {
        px[i] = f[i*3+0]; py[i] = f[i*3+1]; pz[i] = f[i*3+2];
      }
      float4* dst = (float4*)(pts + (size_t)t * 48);
#pragma unroll
      for (int i = 0; i < 12; ++i) dst[i] = buf[i];
    }
    float* dw = dist_ws + (size_t)b * NPTS + (size_t)t * 16;
    float cx, cy, cz;
    if (s0 == 0) {
#pragma unroll
      for (int i = 0; i < 16; ++i) dist[i] = __builtin_inff();
      cx = xb[0]; cy = xb[1]; cz = xb[2];
    } else {
      float4 d0 = *(const float4*)(dw + 0);
      float4 d1 = *(const float4*)(dw + 4);
      float4 d2 = *(const float4*)(dw + 8);
      float4 d3 = *(const float4*)(dw + 12);
      dist[0]=d0.x; dist[1]=d0.y; dist[2]=d0.z; dist[3]=d0.w;
      dist[4]=d1.x; dist[5]=d1.y; dist[6]=d1.z; dist[7]=d1.w;
      dist[8]=d2.x; dist[9]=d2.y; dist[10]=d2.z; dist[11]=d2.w;
      dist[12]=d3.x; dist[13]=d3.y; dist[14]=d3.z; dist[15]=d3.w;
      cx = cst[b*3+0]; cy = cst[b*3+1]; cz = cst[b*3+2];
    }
    int lane = t & 63, wv = t >> 6;

    for (int s = 0; s < FPS_STEPS; ++s) {
      if (t == 0) { outb[s*3+0] = cx; outb[s*3+1] = cy; outb[s*3+2] = cz; }
      float bd = -1.0f; int bslot = 0;
#pragma unroll
      for (int i = 0; i < 16; ++i) {
        float dx = __fsub_rn(px[i], cx);
        float dy = __fsub_rn(py[i], cy);
        float dz = __fsub_rn(pz[i], cz);
        float d  = __fadd_rn(__fadd_rn(__fmul_rn(dx,dx), __fmul_rn(dy,dy)), __fmul_rn(dz,dz));
        float nd = fminf(dist[i], d);
        dist[i] = nd;
        if (nd > bd) { bd = nd; bslot = i; }    // strict >: first max in idx order
      }
      float w = wave_max_dpp(bd);
      float wmax = __int_as_float(__builtin_amdgcn_readlane(__float_as_int(w), 63));
      unsigned long long mk = __ballot(bd == wmax);
      int sl = __ffsll((long long)mk) - 1;      // lowest lane = lowest idx
      int widx = __builtin_amdgcn_readlane(t * 16 + bslot, sl);
      if (lane == 0)
        keys[s & 1][wv] = (((unsigned long long)__float_as_uint(wmax)) << 32)
                          | (unsigned)(8191 - widx);
      __syncthreads();
      unsigned long long bk = keys[s & 1][0];
#pragma unroll
      for (int w2 = 1; w2 < 8; ++w2) {
        unsigned long long o = keys[s & 1][w2];
        if (o > bk) bk = o;
      }
      int idx = 8191 - (int)(unsigned)(bk & 0xffffffffull);
      cx = pts[idx*3+0]; cy = pts[idx*3+1]; cz = pts[idx*3+2];
    }

    *(float4*)(dw + 0)  = make_float4(dist[0], dist[1], dist[2], dist[3]);
    *(float4*)(dw + 4)  = make_float4(dist[4], dist[5], dist[6], dist[7]);
    *(float4*)(dw + 8)  = make_float4(dist[8], dist[9], dist[10], dist[11]);
    *(float4*)(dw + 12) = make_float4(dist[12], dist[13], dist[14], dist[15]);
    if (t == 0) { cst[b*3+0] = cx; cst[b*3+1] = cy; cst[b*3+2] = cz; }
    __syncthreads();
    float* ob = new_xyz + (size_t)b * MCENT * 3 + (size_t)s0 * 3;
    for (int i = t; i < FPS_STEPS * 3; i += 512) ob[i] = outb[i];

  } else if (blk < 72) {
    // ---------------- Ball-query role: phase s0-64 --------------------------
    int ph = s0 - FPS_STEPS;
    if (ph < 0 || ph >= MCENT) return;
    int wv = t >> 6, lane = t & 63;
    int c  = (blk - 8) * 8 + wv;                 // 0..511
    int b  = c >> 6;
    int ci = ph + (c & 63);
    int gm = b * MCENT + ci;
    const float* cc = new_xyz + (size_t)gm * 3;
    float c0 = cc[0], c1 = cc[1], c2 = cc[2];
    float sc = __fadd_rn(__fadd_rn(__fmul_rn(c0,c0), __fmul_rn(c1,c1)), __fmul_rn(c2,c2));
    const float* xb = xyz + (size_t)b * NPTS * 3;

    unsigned cnt = 0;
    for (int j0 = 0; j0 < NPTS; j0 += 64) {
      int j = j0 + lane;
      float x = xb[j*3+0], y = xb[j*3+1], z = xb[j*3+2];
      float sx  = __fadd_rn(__fadd_rn(__fmul_rn(x,x), __fmul_rn(y,y)), __fmul_rn(z,z));
      float dot = __fadd_rn(__fadd_rn(__fmul_rn(c0,x), __fmul_rn(c1,y)), __fmul_rn(c2,z));
      float d2  = __fsub_rn(__fadd_rn(sc, sx), __fmul_rn(2.0f, dot));
      float dist = sqrtf(fmaxf(d2, 0.0f));
      bool in_ = (dist <= 0.5f);
      unsigned long long mask = __ballot(in_);
      unsigned off = (unsigned)__popcll(mask & ((1ull << lane) - 1ull));
      if (in_) {
        unsigned pos = cnt + off;
        if (pos < BQCAP)
          list[wv][pos] = (((unsigned long long)__float_as_uint(dist)) << 32) | (unsigned)j;
      }
      cnt += (unsigned)__popcll(mask);
    }
    if (cnt > BQCAP) cnt = BQCAP;

    unsigned long long e[8];
#pragma unroll
    for (int i = 0; i < 8; ++i) {
      unsigned pos = (unsigned)lane + ((unsigned)i << 6);
      e[i] = (pos < cnt) ? list[wv][pos] : ~0ull;
    }
#define CE_(a_, b_) { bool sw = e[b_] < e[a_]; \
                      unsigned long long lo_ = sw ? e[b_] : e[a_]; \
                      unsigned long long hi_ = sw ? e[a_] : e[b_]; \
                      e[a_] = lo_; e[b_] = hi_; }
    CE_(0,1) CE_(2,3) CE_(4,5) CE_(6,7)
    CE_(0,2) CE_(1,3) CE_(4,6) CE_(5,7)
    CE_(1,2) CE_(5,6)
    CE_(0,4) CE_(1,5) CE_(2,6) CE_(3,7)
    CE_(2,4) CE_(3,5)
    CE_(1,2) CE_(3,4) CE_(5,6)
#undef CE_

    int* gout = gidx + (size_t)gm * KNN;
    int first = 0;
    int kmax = (cnt < (unsigned)KNN) ? (int)cnt : KNN;
    for (int k = 0; k < KNN; ++k) {
      if (k < kmax) {
        unsigned long long wr = wave_min64_dpp(e[0]);
        unsigned lo32 = (unsigned)__builtin_amdgcn_readlane((int)(unsigned)(wr & 0xffffffffull), 63);
        unsigned hi32 = (unsigned)__builtin_amdgcn_readlane((int)(unsigned)(wr >> 32), 63);
        unsigned long long wmin = (((unsigned long long)hi32) << 32) | lo32;
        int idxv = (int)lo32;
        if (k == 0) first = idxv;
        if (lane == 0) gout[k] = idxv;
        bool win = (e[0] == wmin);
#pragma unroll
        for (int i = 0; i < 7; ++i) e[i] = win ? e[i+1] : e[i];
        e[7] = win ? ~0ull : e[7];
      } else {
        if (lane == 0) gout[k] = first;
      }
    }

  } else if (blk < 104) {
    // ---------------- Layer-1 role: phase s0-128 ----------------------------
    int ph = s0 - 2 * FPS_STEPS;
    if (ph < 0 || ph >= MCENT) return;
    int row = (blk - 72) * 512 + t;              // 0..16383
    int c   = row >> 5;                          // centroid seq 0..511
    int k   = row & 31;
    int b   = c >> 6;
    int ci  = ph + (c & 63);
    int p   = b * (MCENT * KNN) + ci * KNN + k;  // global h1 row
    int idx = gidx[p];
    const float* cc = new_xyz + (size_t)(b * MCENT + ci) * 3;
    const float* q  = xyz + (size_t)(b * NPTS + idx) * 3;
    float in[67];
    in[0] = q[0] - cc[0];
    in[1] = q[1] - cc[1];
    in[2] = q[2] - cc[2];
    const float* fr = feats + (size_t)(b * NPTS + idx) * CFEAT;
#pragma unroll
    for (int j = 0; j < 64; j += 4) {
      float4 v = *(const float4*)(fr + j);
      in[3+j] = v.x; in[4+j] = v.y; in[5+j] = v.z; in[6+j] = v.w;
    }
    float* orow = h1 + (size_t)p * 64;
    for (int o4 = 0; o4 < 16; ++o4) {
      const float* w0 = W1 + (size_t)(o4 * 4) * 67;
      float a0 = b1v[o4*4+0], a1 = b1v[o4*4+1], a2 = b1v[o4*4+2], a3 = b1v[o4*4+3];
#pragma unroll
      for (int j = 0; j < 67; ++j) {
        float x = in[j];
        a0 = fmaf(x, w0[j],       a0);
        a1 = fmaf(x, w0[67+j],    a1);
        a2 = fmaf(x, w0[134+j],   a2);
        a3 = fmaf(x, w0[201+j],   a3);
      }
      *(float4*)(orow + o4*4) = make_float4(a0, a1, a2, a3);
    }

  } else {
    // ---------------- L1 BN-stats role: phase s0-192 ------------------------
    int ph = s0 - 3 * FPS_STEPS;
    if (ph < 0 || ph >= MCENT) return;
    int sb = blk - 104;                          // 0..31
    int b  = sb >> 2;
    int rb = (sb & 3) * 512;
    int c  = t & 63, g = t >> 6;                 // 8 groups of 64
    size_t base = (size_t)b * (MCENT * KNN) + (size_t)ph * KNN + rb;
    float s = 0.0f, ss = 0.0f;
    for (int r = g; r < 512; r += 8) {
      float v = h1[(base + r) * 64 + c];
      s += v;
      ss = fmaf(v, v, ss);
    }
    ls[t] = s; lss[t] = ss;
    __syncthreads();
    if (g == 0) {
#pragma unroll
      for (int gg = 1; gg < 8; ++gg) { s += ls[gg*64 + c]; ss += lss[gg*64 + c]; }
      int pblk = (ph >> 6) * 32 + sb;            // 0..511
      part[(size_t)pblk * 128 + c]      = s;
      part[(size_t)pblk * 128 + 64 + c] = ss;
    }
  }
}

// ---------------------------------------------------------------- 4. Layer 2: BN1+GELU then W2, IN-PLACE
__global__ __launch_bounds__(256) void l2_kernel(
    float* __restrict__ h, const float* __restrict__ W,
    const float* __restrict__ bv, const float* __restrict__ bnp,
    const float* __restrict__ btp)
{
  int p = blockIdx.x * 256 + threadIdx.x;
  float* row = h + (size_t)p * 64;
  float in[64];
#pragma unroll
  for (int j = 0; j < 64; j += 4) {
    float4 v = *(const float4*)(row + j);
    in[j+0] = gelu_f((v.x - bnp[j+0]) * bnp[64+j+0] + btp[j+0]);
    in[j+1] = gelu_f((v.y - bnp[j+1]) * bnp[64+j+1] + btp[j+1]);
    in[j+2] = gelu_f((v.z - bnp[j+2]) * bnp[64+j+2] + btp[j+2]);
    in[j+3] = gelu_f((v.w - bnp[j+3]) * bnp[64+j+3] + btp[j+3]);
  }
  for (int o4 = 0; o4 < 16; ++o4) {
    const float* w0 = W + (size_t)(o4 * 4) * 64;
    float a0 = bv[o4*4+0], a1 = bv[o4*4+1], a2 = bv[o4*4+2], a3 = bv[o4*4+3];
#pragma unroll
    for (int j = 0; j < 64; ++j) {
      float x = in[j];
      a0 = fmaf(x, w0[j],      a0);
      a1 = fmaf(x, w0[64+j],   a1);
      a2 = fmaf(x, w0[128+j],  a2);
      a3 = fmaf(x, w0[192+j],  a3);
    }
    *(float4*)(row + o4*4) = make_float4(a0, a1, a2, a3);
  }
}

// ---------------------------------------------------------------- 5. Deterministic BN stats (layer 2)
template<int C>
__global__ __launch_bounds__(256) void stats_kernel(const float* __restrict__ h,
                                                    float* __restrict__ part)
{
  constexpr int G = 256 / C;
  int t = threadIdx.x;
  int c = t % C, g = t / C;
  const float* base = h + (size_t)blockIdx.x * 512 * C;
  float s = 0.0f, ss = 0.0f;
  for (int r = g; r < 512; r += G) {
    float v = base[(size_t)r * C + c];
    s += v;
    ss = fmaf(v, v, ss);
  }
  __shared__ float ls[256], lss[256];
  ls[t] = s; lss[t] = ss;
  __syncthreads();
  if (g == 0) {
    for (int gg = 1; gg < G; ++gg) { s += ls[gg*C + c]; ss += lss[gg*C + c]; }
    part[(size_t)blockIdx.x * (2*C) + c]     = s;
    part[(size_t)blockIdx.x * (2*C) + C + c] = ss;
  }
}

template<int C>
__global__ __launch_bounds__(256) void fin_kernel(const float* __restrict__ part,
                                                  const float* __restrict__ gv,
                                                  float* __restrict__ bn)
{
  int c = blockIdx.x, t = threadIdx.x;
  float s = 0.0f, ss = 0.0f;
  for (int b2 = t; b2 < 512; b2 += 256) {
    s  += part[(size_t)b2 * (2*C) + c];
    ss += part[(size_t)b2 * (2*C) + C + c];
  }
  __shared__ float ls[256], lss[256];
  ls[t] = s; lss[t] = ss;
  __syncthreads();
  for (int k = 128; k > 0; k >>= 1) {
    if (t < k) { ls[t] += ls[t+k]; lss[t] += lss[t+k]; }
    __syncthreads();
  }
  if (t == 0) {
    const float inv_n = 1.0f / 262144.0f;
    float mu  = ls[0] * inv_n;
    float var = fmaxf(lss[0] * inv_n - mu * mu, 0.0f);
    bn[c]     = mu;
    bn[C + c] = gv[c] / sqrtf(var + EPS_F);
  }
}

// ---------------------------------------------------------------- 5b. In-place BN2+GELU activation (small-ws path only)
__global__ __launch_bounds__(256) void act_kernel(float* __restrict__ h,
                                                  const float* __restrict__ bnp,
                                                  const float* __restrict__ btp)
{
  int p = blockIdx.x * 256 + threadIdx.x;
  float* row = h + (size_t)p * 64;
#pragma unroll
  for (int j = 0; j < 64; j += 4) {
    float4 v = *(const float4*)(row + j);
    v.x = gelu_f((v.x - bnp[j+0]) * bnp[64+j+0] + btp[j+0]);
    v.y = gelu_f((v.y - bnp[j+1]) * bnp[64+j+1] + btp[j+1]);
    v.z = gelu_f((v.z - bnp[j+2]) * bnp[64+j+2] + btp[j+2]);
    v.w = gelu_f((v.w - bnp[j+3]) * bnp[64+j+3] + btp[j+3]);
    *(float4*)(row + j) = v;
  }
}

// ---------------------------------------------------------------- 6a. Layer-3 stats (small-ws path; R10-verified)
__global__ __launch_bounds__(256, 1) void l3stats_kernel(
    const float* __restrict__ g2, const float* __restrict__ W3,
    const float* __restrict__ b3, float* __restrict__ part)
{
  int t = threadIdx.x;
  int gb = blockIdx.x >> 2, chunk = blockIdx.x & 3;
  int og0 = chunk * 32;
  int p = gb * 256 + t;
  const float* row = g2 + (size_t)p * 64;
  float in[64];
#pragma unroll
  for (int j = 0; j < 64; j += 4) {
    float4 v = *(const float4*)(row + j);
    in[j+0] = v.x; in[j+1] = v.y; in[j+2] = v.z; in[j+3] = v.w;
  }
  float s_[32], q_[32];
  for (int o4 = 0; o4 < 8; ++o4) {
    const float* w0 = W3 + (size_t)(og0 + o4 * 4) * 64;
    float a0 = b3[og0+o4*4+0], a1 = b3[og0+o4*4+1], a2 = b3[og0+o4*4+2], a3 = b3[og0+o4*4+3];
#pragma unroll
    for (int j = 0; j < 64; ++j) {
      float x = in[j];
      a0 = fmaf(x, w0[j],      a0);
      a1 = fmaf(x, w0[64+j],   a1);
      a2 = fmaf(x, w0[128+j],  a2);
      a3 = fmaf(x, w0[192+j],  a3);
    }
    int o = o4 * 4;
    s_[o]=a0; s_[o+1]=a1; s_[o+2]=a2; s_[o+3]=a3;
    q_[o]=a0*a0; q_[o+1]=a1*a1; q_[o+2]=a2*a2; q_[o+3]=a3*a3;
  }

  int wv = t >> 6, lane = t & 63;
  tree_step<1,16>(s_, q_, lane);
  tree_step<2, 8>(s_, q_, lane);
  tree_step<4, 4>(s_, q_, lane);
  tree_step<8, 2>(s_, q_, lane);
  tree_step<16,1>(s_, q_, lane);
  s_[0] += __shfl_xor(s_[0], 32, 64);
  q_[0] += __shfl_xor(q_[0], 32, 64);

  int ch = (int)(__brev((unsigned)(lane & 31)) >> 27);
  float* pw = part + ((size_t)blockIdx.x * 4 + wv) * 64;
  if (lane < 32) { pw[ch] = s_[0]; pw[32 + ch] = q_[0]; }
}

// ---------------------------------------------------------------- 6b. Layer-3 stats + h3t f16 emit (big-ws path)
// BN2+GELU fused at load (h1 is raw l2 output); GEMM acc written transposed
// h3t[gm][oc][k] as f16 (error ~2^-11 << 0.1325 threshold); stats stay f32.
__global__ __launch_bounds__(256, 1) void l3stats_h3_kernel(
    const float* __restrict__ h1, const float* __restrict__ W3,
    const float* __restrict__ b3, const float* __restrict__ bnp2,
    const float* __restrict__ btp2, float* __restrict__ part,
    __half* __restrict__ h3t)
{
  int t = threadIdx.x;
  int gb = blockIdx.x >> 2, chunk = blockIdx.x & 3;
  int og0 = chunk * 32;
  int p = gb * 256 + t;
  const float* row = h1 + (size_t)p * 64;
  float in[64];
#pragma unroll
  for (int j = 0; j < 64; j += 4) {
    float4 v = *(const float4*)(row + j);
    in[j+0] = gelu_f((v.x - bnp2[j+0]) * bnp2[64+j+0] + btp2[j+0]);
    in[j+1] = gelu_f((v.y - bnp2[j+1]) * bnp2[64+j+1] + btp2[j+1]);
    in[j+2] = gelu_f((v.z - bnp2[j+2]) * bnp2[64+j+2] + btp2[j+2]);
    in[j+3] = gelu_f((v.w - bnp2[j+3]) * bnp2[64+j+3] + btp2[j+3]);
  }
  int gm = p >> 5, kk = p & 31;
  __half* hb = h3t + ((size_t)gm * 128 + og0) * 32 + kk;   // + oc*32 per channel
  float s_[32], q_[32];
  for (int o4 = 0; o4 < 8; ++o4) {
    const float* w0 = W3 + (size_t)(og0 + o4 * 4) * 64;
    float a0 = b3[og0+o4*4+0], a1 = b3[og0+o4*4+1], a2 = b3[og0+o4*4+2], a3 = b3[og0+o4*4+3];
#pragma unroll
    for (int j = 0; j < 64; ++j) {
      float x = in[j];
      a0 = fmaf(x, w0[j],      a0);
      a1 = fmaf(x, w0[64+j],   a1);
      a2 = fmaf(x, w0[128+j],  a2);
      a3 = fmaf(x, w0[192+j],  a3);
    }
    int o = o4 * 4;
    hb[(size_t)(o+0)*32] = __float2half_rn(a0);
    hb[(size_t)(o+1)*32] = __float2half_rn(a1);
    hb[(size_t)(o+2)*32] = __float2half_rn(a2);
    hb[(size_t)(o+3)*32] = __float2half_rn(a3);
    s_[o]=a0; s_[o+1]=a1; s_[o+2]=a2; s_[o+3]=a3;
    q_[o]=a0*a0; q_[o+1]=a1*a1; q_[o+2]=a2*a2; q_[o+3]=a3*a3;
  }

  int wv = t >> 6, lane = t & 63;
  tree_step<1,16>(s_, q_, lane);
  tree_step<2, 8>(s_, q_, lane);
  tree_step<4, 4>(s_, q_, lane);
  tree_step<8, 2>(s_, q_, lane);
  tree_step<16,1>(s_, q_, lane);
  s_[0] += __shfl_xor(s_[0], 32, 64);
  q_[0] += __shfl_xor(q_[0], 32, 64);

  int ch = (int)(__brev((unsigned)(lane & 31)) >> 27);
  float* pw = part + ((size_t)blockIdx.x * 4 + wv) * 64;
  if (lane < 32) { pw[ch] = s_[0]; pw[32 + ch] = q_[0]; }
}

__global__ __launch_bounds__(256) void fin3_kernel(const float* __restrict__ part,
                                                   const float* __restrict__ gv,
                                                   float* __restrict__ bn)
{
  int c = blockIdx.x, t = threadIdx.x;
  int chunk = c >> 5, j = c & 31;
  float s = 0.0f, ss = 0.0f;
  for (int gb = t; gb < 1024; gb += 256) {
    int blk = gb * 4 + chunk;
#pragma unroll
    for (int wv = 0; wv < 4; ++wv) {
      const float* pw = part + ((size_t)blk * 4 + wv) * 64;
      s  += pw[j];
      ss += pw[32 + j];
    }
  }
  __shared__ float ls[256], lss[256];
  ls[t] = s; lss[t] = ss;
  __syncthreads();
  for (int k = 128; k > 0; k >>= 1) {
    if (t < k) { ls[t] += ls[t+k]; lss[t] += lss[t+k]; }
    __syncthreads();
  }
  if (t == 0) {
    const float inv_n = 1.0f / 262144.0f;
    float mu  = ls[0] * inv_n;
    float var = fmaxf(lss[0] * inv_n - mu * mu, 0.0f);
    bn[c]       = mu;
    bn[128 + c] = gv[c] / sqrtf(var + EPS_F);
  }
}

// ---------------------------------------------------------------- 7a. pool3 (small-ws path; R10-verified recompute)
__global__ __launch_bounds__(256, 1) void pool3_kernel(
    const float* __restrict__ g2, const float* __restrict__ W3,
    const float* __restrict__ b3,
    const float* __restrict__ bnp3,
    const float* __restrict__ btp3,
    float* __restrict__ out1)
{
  int t = threadIdx.x;
  int gb = blockIdx.x >> 2, chunk = blockIdx.x & 3;
  int og0 = chunk * 32;
  int p = gb * 256 + t;
  const float* row = g2 + (size_t)p * 64;
  float in[64];
#pragma unroll
  for (int j = 0; j < 64; j += 4) {
    float4 v = *(const float4*)(row + j);
    in[j+0] = v.x; in[j+1] = v.y; in[j+2] = v.z; in[j+3] = v.w;
  }
  float g_[32];
  for (int o4 = 0; o4 < 8; ++o4) {
    const float* w0 = W3 + (size_t)(og0 + o4 * 4) * 64;
    float a0 = b3[og0+o4*4+0], a1 = b3[og0+o4*4+1], a2 = b3[og0+o4*4+2], a3 = b3[og0+o4*4+3];
#pragma unroll
    for (int j = 0; j < 64; ++j) {
      float x = in[j];
      a0 = fmaf(x, w0[j],      a0);
      a1 = fmaf(x, w0[64+j],   a1);
      a2 = fmaf(x, w0[128+j],  a2);
      a3 = fmaf(x, w0[192+j],  a3);
    }
    int oc0 = og0 + o4 * 4, o = o4 * 4;
    g_[o]   = gelu_f((a0 - bnp3[oc0+0]) * bnp3[128+oc0+0] + btp3[oc0+0]);
    g_[o+1] = gelu_f((a1 - bnp3[oc0+1]) * bnp3[128+oc0+1] + btp3[oc0+1]);
    g_[o+2] = gelu_f((a2 - bnp3[oc0+2]) * bnp3[128+oc0+2] + btp3[oc0+2]);
    g_[o+3] = gelu_f((a3 - bnp3[oc0+3]) * bnp3[128+oc0+3] + btp3[oc0+3]);
  }

  ptree_step<1,16>(g_, t);
  ptree_step<2, 8>(g_, t);
  ptree_step<4, 4>(g_, t);
  ptree_step<8, 2>(g_, t);
  ptree_step<16,1>(g_, t);

  int ch = (int)(__brev((unsigned)(t & 31)) >> 27);
  int gm = gb * 8 + (t >> 5);
  out1[(size_t)gm * 128 + og0 + ch] = g_[0];
}

// ---------------------------------------------------------------- 7b. pool3t (big-ws path): read h3t f16, BN3+GELU+max
// thread u -> (gm, oc); 64B contiguous load; coalesced across lanes.
__global__ __launch_bounds__(256) void pool3t_kernel(
    const __half* __restrict__ h3t,
    const float* __restrict__ bnp3, const float* __restrict__ btp3,
    float* __restrict__ out1)
{
  int u = blockIdx.x * 256 + threadIdx.x;      // 0..1048575
  int gm = u >> 7, oc = u & 127;
  float mu = bnp3[oc], a = bnp3[128 + oc], bt = btp3[oc];
  const uint4* src = (const uint4*)(h3t + ((size_t)gm * 128 + oc) * 32);
  float mx = -__builtin_inff();
#pragma unroll
  for (int i = 0; i < 4; ++i) {
    uint4 v = src[i];
    unsigned wds[4] = {v.x, v.y, v.z, v.w};
#pragma unroll
    for (int w2 = 0; w2 < 4; ++w2) {
      __half2 hp = *reinterpret_cast<const __half2*>(&wds[w2]);
      float2 f = __half22float2(hp);
      float x0 = gelu_f((f.x - mu) * a + bt);
      float x1 = gelu_f((f.y - mu) * a + bt);
      mx = fmaxf(mx, fmaxf(x0, x1));
    }
  }
  out1[u] = mx;
}

// ---------------------------------------------------------------- diagnostic fill
__global__ void fill_kernel(float* __restrict__ out1) {
  out1[blockIdx.x * 256 + threadIdx.x] = 1.0e6f;
}

// ---------------------------------------------------------------- launch
extern "C" void kernel_launch(void* const* d_in, const int* in_sizes, int n_in,
                              void* d_out, int out_size, void* d_ws, size_t ws_size,
                              hipStream_t stream)
{
  (void)in_sizes; (void)n_in; (void)out_size;
  const float* xyz   = (const float*)d_in[0];
  const float* feats = (const float*)d_in[1];
  const float* W1  = (const float*)d_in[2];
  const float* b1  = (const float*)d_in[3];
  const float* g1  = (const float*)d_in[4];
  const float* bt1 = (const float*)d_in[5];
  const float* W2  = (const float*)d_in[6];
  const float* b2  = (const float*)d_in[7];
  const float* g2  = (const float*)d_in[8];
  const float* bt2 = (const float*)d_in[9];
  const float* W3  = (const float*)d_in[10];
  const float* b3  = (const float*)d_in[11];
  const float* g3  = (const float*)d_in[12];
  const float* bt3 = (const float*)d_in[13];

  float* out0 = (float*)d_out;
  float* out1 = out0 + (size_t)BATCH * MCENT * 3;

  char* ws = (char*)d_ws;
  int*   gidx    = (int*)(ws + 0);
  float* part    = (float*)(ws + (1u << 20));
  float* bn0     = (float*)(ws + 5u * (1u << 20));
  float* bn1     = bn0 + 128;
  float* bn2     = bn0 + 256;
  float* dist_ws = (float*)(ws + 5u * (1u << 20) + 65536u);
  float* cst     = (float*)(ws + 5u * (1u << 20) + 65536u + 262144u);
  float* h1      = (float*)(ws + 6u * (1u << 20));
  __half* h3t    = (__half*)(ws + 70u * (1u << 20));

  if (ws_size < WS_NEED_SMALL) {
    fill_kernel<<<4096, 256, 0, stream>>>(out1);
    return;
  }

  // 19 dispatches: FPS phases 0..15; bq lags 1, l1 lags 2, L1-stats lags 3.
  for (int s0 = 0; s0 <= MCENT + 2 * FPS_STEPS; s0 += FPS_STEPS)
    mega_kernel<<<136, 512, 0, stream>>>(xyz, out0, dist_ws, cst, s0,
                                         gidx, feats, W1, b1, h1, part);

  fin_kernel<64><<<64, 256, 0, stream>>>(part, g1, bn0);
  l2_kernel<<<1024, 256, 0, stream>>>(h1, W2, b2, bn0, bt1);
  stats_kernel<64><<<512, 256, 0, stream>>>(h1, part);
  fin_kernel<64><<<64, 256, 0, stream>>>(part, g2, bn1);

  if (ws_size >= WS_NEED_BIG) {
    // big-ws path: fused BN2+GELU, f16 h3 materialization, light pool.
    l3stats_h3_kernel<<<4096, 256, 0, stream>>>(h1, W3, b3, bn1, bt2, part, h3t);
    fin3_kernel<<<128, 256, 0, stream>>>(part, g3, bn2);
    pool3t_kernel<<<4096, 256, 0, stream>>>(h3t, bn2, bt3, out1);
  } else {
    // small-ws fallback: R13-verified sequence.
    act_kernel<<<1024, 256, 0, stream>>>(h1, bn1, bt2);
    l3stats_kernel<<<4096, 256, 0, stream>>>(h1, W3, b3, part);
    fin3_kernel<<<128, 256, 0, stream>>>(part, g3, bn2);
    pool3_kernel<<<4096, 256, 0, stream>>>(h1, W3, b3, bn2, bt3, out1);
  }
}

// Round 15
// 1407.209 us; speedup vs baseline: 1.6002x; 1.0063x over previous
//
#include <hip/hip_runtime.h>
#include <hip/hip_fp16.h>
#include <cstdint>
#include <cstddef>

#define BATCH 8
#define NPTS  8192
#define MCENT 1024
#define KNN   32
#define CFEAT 64
#define EPS_F 1e-5f

// Workspace layout:
//   gidx : [0, 1MiB)          part : [1MiB, 5MiB)
//   bn   : [5MiB, +2KiB)      fps dist : [5MiB+64KiB, +256KiB)  cst : after
//   h1   : [6MiB, 70MiB)      f32 [262144][64]
//   h3t  : [70MiB, 134MiB)    f16 [8192][128][32]  (big-ws path only)
#define WS_NEED_SMALL 73400320ull
#define WS_NEED_BIG   140509184ull

// LESSONS (R9/R11/R12/R14 — do not retry):
//  * >~100 live floats/thread in GEMM-reduce kernels spills / tanks occupancy
//    (R11: pool3 130->503us). Channel arrays <=32; in[64] not live across chunks.
//  * Two FPS batches sharing one __syncthreads are barrier-coupled; global
//    coord lookup on the serial chain adds ~400cy (R12: mega 60->100us).
//  * Fusing BN+GELU into a 4-chunk kernel recomputes gelu 4x/row: costs 65us
//    to save act's 20us (R14: l3stats_h3 177us). Keep act separate.

// ---------------------------------------------------------------- fast erf GELU
__device__ __forceinline__ float erf_fast(float x) {
  float a = fabsf(x);
  float t = __builtin_amdgcn_rcpf(fmaf(0.3275911f, a, 1.0f));
  float p = fmaf(1.061405429f, t, -1.453152027f);
  p = fmaf(p, t, 1.421413741f);
  p = fmaf(p, t, -0.284496736f);
  p = fmaf(p, t, 0.254829592f);
  float e = __expf(-a * a);
  float y = fmaf(-p * t, e, 1.0f);
  return copysignf(y, x);
}
__device__ __forceinline__ float gelu_f(float x) {
  return 0.5f * x * (1.0f + erf_fast(x * 0.70710678118654752440f));
}

// DPP wave64 reduce helpers.
template<int CTRL>
__device__ __forceinline__ float dpp_max_step(float v) {
  int s = __builtin_amdgcn_update_dpp(__float_as_int(v), __float_as_int(v),
                                      CTRL, 0xf, 0xf, false);
  return fmaxf(v, __int_as_float(s));
}
__device__ __forceinline__ float wave_max_dpp(float v) {
  v = dpp_max_step<0x111>(v);
  v = dpp_max_step<0x112>(v);
  v = dpp_max_step<0x114>(v);
  v = dpp_max_step<0x118>(v);
  v = dpp_max_step<0x142>(v);
  v = dpp_max_step<0x143>(v);
  return v;                    // lane 63 = wave max
}
template<int CTRL>
__device__ __forceinline__ unsigned long long dpp_min64_step(unsigned long long v) {
  int lo = __builtin_amdgcn_update_dpp((int)(unsigned)(v & 0xffffffffull),
                                       (int)(unsigned)(v & 0xffffffffull),
                                       CTRL, 0xf, 0xf, false);
  int hi = __builtin_amdgcn_update_dpp((int)(unsigned)(v >> 32),
                                       (int)(unsigned)(v >> 32),
                                       CTRL, 0xf, 0xf, false);
  unsigned long long o = (((unsigned long long)(unsigned)hi) << 32) | (unsigned)lo;
  return o < v ? o : v;
}
__device__ __forceinline__ unsigned long long wave_min64_dpp(unsigned long long v) {
  v = dpp_min64_step<0x111>(v);
  v = dpp_min64_step<0x112>(v);
  v = dpp_min64_step<0x114>(v);
  v = dpp_min64_step<0x118>(v);
  v = dpp_min64_step<0x142>(v);
  v = dpp_min64_step<0x143>(v);
  return v;                    // lane 63 = wave min
}

// Channel-exchange tree steps, COMPILE-TIME bounds (rule #20).
template<int M, int HALF>
__device__ __forceinline__ void tree_step(float* s_, float* q_, int lane) {
  bool up = (lane & M) != 0;
#pragma unroll
  for (int j = 0; j < HALF; ++j) {
    float ks = up ? s_[j+HALF] : s_[j];
    float ds = up ? s_[j]      : s_[j+HALF];
    s_[j] = ks + __shfl_xor(ds, M, 64);
    float kq = up ? q_[j+HALF] : q_[j];
    float dq = up ? q_[j]      : q_[j+HALF];
    q_[j] = kq + __shfl_xor(dq, M, 64);
  }
}
template<int M, int HALF>
__device__ __forceinline__ void ptree_step(float* g_, int kbit) {
  bool up = (kbit & M) != 0;
#pragma unroll
  for (int j = 0; j < HALF; ++j) {
    float kv = up ? g_[j+HALF] : g_[j];
    float dv = up ? g_[j]      : g_[j+HALF];
    g_[j] = fmaxf(kv, __shfl_xor(dv, M, 64));
  }
}

// ---------------------------------------------------------------- 1. MEGA kernel
// One dispatch per 64-step FPS phase; role-split blocks use idle CUs:
//   blk 0-7    : FPS phase s0                (8 CUs)
//   blk 8-71   : ball query, phase s0-64     (prev dispatch's centroids)
//   blk 72-103 : layer-1,   phase s0-128
//   blk 104-135: L1 BN stats, phase s0-192   (rows written prev dispatch)
// Same-stream dispatch ordering guarantees producer visibility.
#define FPS_STEPS 64
#define BQCAP 512
__global__ __launch_bounds__(512, 1) void mega_kernel(
    const float* __restrict__ xyz, float* __restrict__ new_xyz,
    float* __restrict__ dist_ws, float* __restrict__ cst, int s0,
    int* __restrict__ gidx, const float* __restrict__ feats,
    const float* __restrict__ W1, const float* __restrict__ b1v,
    float* __restrict__ h1, float* __restrict__ part)
{
  __shared__ float pts[NPTS * 3];                  // 96 KiB (fps)
  __shared__ float outb[FPS_STEPS * 3];
  __shared__ unsigned long long keys[2][8];
  __shared__ unsigned long long list[8][BQCAP];    // 32 KiB (bq)
  __shared__ float ls[512], lss[512];              // 4 KiB (stats)
  int blk = blockIdx.x, t = threadIdx.x;

  if (blk < 8) {
    // ---------------- FPS role (verified bit-exact jnp arithmetic) ----------
    if (s0 >= MCENT) return;
    int b = blk;
    const float* xb = xyz + (size_t)b * NPTS * 3;
    float px[16], py[16], pz[16], dist[16];
    {
      const float4* src = (const float4*)(xb + (size_t)t * 48);
      float4 buf[12];
#pragma unroll
      for (int i = 0; i < 12; ++i) buf[i] = src[i];
      const float* f = (const float*)buf;
#pragma unroll
      for (int i = 0; i < 16; ++i) {
        px[i] = f[i*3+0]; py[i] = f[i*3+1]; pz[i] = f[i*3+2];
      }
      float4* dst = (float4*)(pts + (size_t)t * 48);
#pragma unroll
      for (int i = 0; i < 12; ++i) dst[i] = buf[i];
    }
    float* dw = dist_ws + (size_t)b * NPTS + (size_t)t * 16;
    float cx, cy, cz;
    if (s0 == 0) {
#pragma unroll
      for (int i = 0; i < 16; ++i) dist[i] = __builtin_inff();
      cx = xb[0]; cy = xb[1]; cz = xb[2];
    } else {
      float4 d0 = *(const float4*)(dw + 0);
      float4 d1 = *(const float4*)(dw + 4);
      float4 d2 = *(const float4*)(dw + 8);
      float4 d3 = *(const float4*)(dw + 12);
      dist[0]=d0.x; dist[1]=d0.y; dist[2]=d0.z; dist[3]=d0.w;
      dist[4]=d1.x; dist[5]=d1.y; dist[6]=d1.z; dist[7]=d1.w;
      dist[8]=d2.x; dist[9]=d2.y; dist[10]=d2.z; dist[11]=d2.w;
      dist[12]=d3.x; dist[13]=d3.y; dist[14]=d3.z; dist[15]=d3.w;
      cx = cst[b*3+0]; cy = cst[b*3+1]; cz = cst[b*3+2];
    }
    int lane = t & 63, wv = t >> 6;

    for (int s = 0; s < FPS_STEPS; ++s) {
      if (t == 0) { outb[s*3+0] = cx; outb[s*3+1] = cy; outb[s*3+2] = cz; }
      float bd = -1.0f; int bslot = 0;
#pragma unroll
      for (int i = 0; i < 16; ++i) {
        float dx = __fsub_rn(px[i], cx);
        float dy = __fsub_rn(py[i], cy);
        float dz = __fsub_rn(pz[i], cz);
        float d  = __fadd_rn(__fadd_rn(__fmul_rn(dx,dx), __fmul_rn(dy,dy)), __fmul_rn(dz,dz));
        float nd = fminf(dist[i], d);
        dist[i] = nd;
        if (nd > bd) { bd = nd; bslot = i; }    // strict >: first max in idx order
      }
      float w = wave_max_dpp(bd);
      float wmax = __int_as_float(__builtin_amdgcn_readlane(__float_as_int(w), 63));
      unsigned long long mk = __ballot(bd == wmax);
      int sl = __ffsll((long long)mk) - 1;      // lowest lane = lowest idx
      int widx = __builtin_amdgcn_readlane(t * 16 + bslot, sl);
      if (lane == 0)
        keys[s & 1][wv] = (((unsigned long long)__float_as_uint(wmax)) << 32)
                          | (unsigned)(8191 - widx);
      __syncthreads();
      unsigned long long bk = keys[s & 1][0];
#pragma unroll
      for (int w2 = 1; w2 < 8; ++w2) {
        unsigned long long o = keys[s & 1][w2];
        if (o > bk) bk = o;
      }
      int idx = 8191 - (int)(unsigned)(bk & 0xffffffffull);
      cx = pts[idx*3+0]; cy = pts[idx*3+1]; cz = pts[idx*3+2];
    }

    *(float4*)(dw + 0)  = make_float4(dist[0], dist[1], dist[2], dist[3]);
    *(float4*)(dw + 4)  = make_float4(dist[4], dist[5], dist[6], dist[7]);
    *(float4*)(dw + 8)  = make_float4(dist[8], dist[9], dist[10], dist[11]);
    *(float4*)(dw + 12) = make_float4(dist[12], dist[13], dist[14], dist[15]);
    if (t == 0) { cst[b*3+0] = cx; cst[b*3+1] = cy; cst[b*3+2] = cz; }
    __syncthreads();
    float* ob = new_xyz + (size_t)b * MCENT * 3 + (size_t)s0 * 3;
    for (int i = t; i < FPS_STEPS * 3; i += 512) ob[i] = outb[i];

  } else if (blk < 72) {
    // ---------------- Ball-query role: phase s0-64 --------------------------
    int ph = s0 - FPS_STEPS;
    if (ph < 0 || ph >= MCENT) return;
    int wv = t >> 6, lane = t & 63;
    int c  = (blk - 8) * 8 + wv;                 // 0..511
    int b  = c >> 6;
    int ci = ph + (c & 63);
    int gm = b * MCENT + ci;
    const float* cc = new_xyz + (size_t)gm * 3;
    float c0 = cc[0], c1 = cc[1], c2 = cc[2];
    float sc = __fadd_rn(__fadd_rn(__fmul_rn(c0,c0), __fmul_rn(c1,c1)), __fmul_rn(c2,c2));
    const float* xb = xyz + (size_t)b * NPTS * 3;

    unsigned cnt = 0;
    for (int j0 = 0; j0 < NPTS; j0 += 64) {
      int j = j0 + lane;
      float x = xb[j*3+0], y = xb[j*3+1], z = xb[j*3+2];
      float sx  = __fadd_rn(__fadd_rn(__fmul_rn(x,x), __fmul_rn(y,y)), __fmul_rn(z,z));
      float dot = __fadd_rn(__fadd_rn(__fmul_rn(c0,x), __fmul_rn(c1,y)), __fmul_rn(c2,z));
      float d2  = __fsub_rn(__fadd_rn(sc, sx), __fmul_rn(2.0f, dot));
      float dist = sqrtf(fmaxf(d2, 0.0f));
      bool in_ = (dist <= 0.5f);
      unsigned long long mask = __ballot(in_);
      unsigned off = (unsigned)__popcll(mask & ((1ull << lane) - 1ull));
      if (in_) {
        unsigned pos = cnt + off;
        if (pos < BQCAP)
          list[wv][pos] = (((unsigned long long)__float_as_uint(dist)) << 32) | (unsigned)j;
      }
      cnt += (unsigned)__popcll(mask);
    }
    if (cnt > BQCAP) cnt = BQCAP;

    unsigned long long e[8];
#pragma unroll
    for (int i = 0; i < 8; ++i) {
      unsigned pos = (unsigned)lane + ((unsigned)i << 6);
      e[i] = (pos < cnt) ? list[wv][pos] : ~0ull;
    }
#define CE_(a_, b_) { bool sw = e[b_] < e[a_]; \
                      unsigned long long lo_ = sw ? e[b_] : e[a_]; \
                      unsigned long long hi_ = sw ? e[a_] : e[b_]; \
                      e[a_] = lo_; e[b_] = hi_; }
    CE_(0,1) CE_(2,3) CE_(4,5) CE_(6,7)
    CE_(0,2) CE_(1,3) CE_(4,6) CE_(5,7)
    CE_(1,2) CE_(5,6)
    CE_(0,4) CE_(1,5) CE_(2,6) CE_(3,7)
    CE_(2,4) CE_(3,5)
    CE_(1,2) CE_(3,4) CE_(5,6)
#undef CE_

    int* gout = gidx + (size_t)gm * KNN;
    int first = 0;
    int kmax = (cnt < (unsigned)KNN) ? (int)cnt : KNN;
    for (int k = 0; k < KNN; ++k) {
      if (k < kmax) {
        unsigned long long wr = wave_min64_dpp(e[0]);
        unsigned lo32 = (unsigned)__builtin_amdgcn_readlane((int)(unsigned)(wr & 0xffffffffull), 63);
        unsigned hi32 = (unsigned)__builtin_amdgcn_readlane((int)(unsigned)(wr >> 32), 63);
        unsigned long long wmin = (((unsigned long long)hi32) << 32) | lo32;
        int idxv = (int)lo32;
        if (k == 0) first = idxv;
        if (lane == 0) gout[k] = idxv;
        bool win = (e[0] == wmin);
#pragma unroll
        for (int i = 0; i < 7; ++i) e[i] = win ? e[i+1] : e[i];
        e[7] = win ? ~0ull : e[7];
      } else {
        if (lane == 0) gout[k] = first;
      }
    }

  } else if (blk < 104) {
    // ---------------- Layer-1 role: phase s0-128 ----------------------------
    int ph = s0 - 2 * FPS_STEPS;
    if (ph < 0 || ph >= MCENT) return;
    int row = (blk - 72) * 512 + t;              // 0..16383
    int c   = row >> 5;                          // centroid seq 0..511
    int k   = row & 31;
    int b   = c >> 6;
    int ci  = ph + (c & 63);
    int p   = b * (MCENT * KNN) + ci * KNN + k;  // global h1 row
    int idx = gidx[p];
    const float* cc = new_xyz + (size_t)(b * MCENT + ci) * 3;
    const float* q  = xyz + (size_t)(b * NPTS + idx) * 3;
    float in[67];
    in[0] = q[0] - cc[0];
    in[1] = q[1] - cc[1];
    in[2] = q[2] - cc[2];
    const float* fr = feats + (size_t)(b * NPTS + idx) * CFEAT;
#pragma unroll
    for (int j = 0; j < 64; j += 4) {
      float4 v = *(const float4*)(fr + j);
      in[3+j] = v.x; in[4+j] = v.y; in[5+j] = v.z; in[6+j] = v.w;
    }
    float* orow = h1 + (size_t)p * 64;
    for (int o4 = 0; o4 < 16; ++o4) {
      const float* w0 = W1 + (size_t)(o4 * 4) * 67;
      float a0 = b1v[o4*4+0], a1 = b1v[o4*4+1], a2 = b1v[o4*4+2], a3 = b1v[o4*4+3];
#pragma unroll
      for (int j = 0; j < 67; ++j) {
        float x = in[j];
        a0 = fmaf(x, w0[j],       a0);
        a1 = fmaf(x, w0[67+j],    a1);
        a2 = fmaf(x, w0[134+j],   a2);
        a3 = fmaf(x, w0[201+j],   a3);
      }
      *(float4*)(orow + o4*4) = make_float4(a0, a1, a2, a3);
    }

  } else {
    // ---------------- L1 BN-stats role: phase s0-192 ------------------------
    int ph = s0 - 3 * FPS_STEPS;
    if (ph < 0 || ph >= MCENT) return;
    int sb = blk - 104;                          // 0..31
    int b  = sb >> 2;
    int rb = (sb & 3) * 512;
    int c  = t & 63, g = t >> 6;                 // 8 groups of 64
    size_t base = (size_t)b * (MCENT * KNN) + (size_t)ph * KNN + rb;
    float s = 0.0f, ss = 0.0f;
    for (int r = g; r < 512; r += 8) {
      float v = h1[(base + r) * 64 + c];
      s += v;
      ss = fmaf(v, v, ss);
    }
    ls[t] = s; lss[t] = ss;
    __syncthreads();
    if (g == 0) {
#pragma unroll
      for (int gg = 1; gg < 8; ++gg) { s += ls[gg*64 + c]; ss += lss[gg*64 + c]; }
      int pblk = (ph >> 6) * 32 + sb;            // 0..511
      part[(size_t)pblk * 128 + c]      = s;
      part[(size_t)pblk * 128 + 64 + c] = ss;
    }
  }
}

// ---------------------------------------------------------------- 4. Layer 2: BN1+GELU then W2, IN-PLACE
__global__ __launch_bounds__(256) void l2_kernel(
    float* __restrict__ h, const float* __restrict__ W,
    const float* __restrict__ bv, const float* __restrict__ bnp,
    const float* __restrict__ btp)
{
  int p = blockIdx.x * 256 + threadIdx.x;
  float* row = h + (size_t)p * 64;
  float in[64];
#pragma unroll
  for (int j = 0; j < 64; j += 4) {
    float4 v = *(const float4*)(row + j);
    in[j+0] = gelu_f((v.x - bnp[j+0]) * bnp[64+j+0] + btp[j+0]);
    in[j+1] = gelu_f((v.y - bnp[j+1]) * bnp[64+j+1] + btp[j+1]);
    in[j+2] = gelu_f((v.z - bnp[j+2]) * bnp[64+j+2] + btp[j+2]);
    in[j+3] = gelu_f((v.w - bnp[j+3]) * bnp[64+j+3] + btp[j+3]);
  }
  for (int o4 = 0; o4 < 16; ++o4) {
    const float* w0 = W + (size_t)(o4 * 4) * 64;
    float a0 = bv[o4*4+0], a1 = bv[o4*4+1], a2 = bv[o4*4+2], a3 = bv[o4*4+3];
#pragma unroll
    for (int j = 0; j < 64; ++j) {
      float x = in[j];
      a0 = fmaf(x, w0[j],      a0);
      a1 = fmaf(x, w0[64+j],   a1);
      a2 = fmaf(x, w0[128+j],  a2);
      a3 = fmaf(x, w0[192+j],  a3);
    }
    *(float4*)(row + o4*4) = make_float4(a0, a1, a2, a3);
  }
}

// ---------------------------------------------------------------- 5. Deterministic BN stats (layer 2)
template<int C>
__global__ __launch_bounds__(256) void stats_kernel(const float* __restrict__ h,
                                                    float* __restrict__ part)
{
  constexpr int G = 256 / C;
  int t = threadIdx.x;
  int c = t % C, g = t / C;
  const float* base = h + (size_t)blockIdx.x * 512 * C;
  float s = 0.0f, ss = 0.0f;
  for (int r = g; r < 512; r += G) {
    float v = base[(size_t)r * C + c];
    s += v;
    ss = fmaf(v, v, ss);
  }
  __shared__ float ls[256], lss[256];
  ls[t] = s; lss[t] = ss;
  __syncthreads();
  if (g == 0) {
    for (int gg = 1; gg < G; ++gg) { s += ls[gg*C + c]; ss += lss[gg*C + c]; }
    part[(size_t)blockIdx.x * (2*C) + c]     = s;
    part[(size_t)blockIdx.x * (2*C) + C + c] = ss;
  }
}

template<int C>
__global__ __launch_bounds__(256) void fin_kernel(const float* __restrict__ part,
                                                  const float* __restrict__ gv,
                                                  float* __restrict__ bn)
{
  int c = blockIdx.x, t = threadIdx.x;
  float s = 0.0f, ss = 0.0f;
  for (int b2 = t; b2 < 512; b2 += 256) {
    s  += part[(size_t)b2 * (2*C) + c];
    ss += part[(size_t)b2 * (2*C) + C + c];
  }
  __shared__ float ls[256], lss[256];
  ls[t] = s; lss[t] = ss;
  __syncthreads();
  for (int k = 128; k > 0; k >>= 1) {
    if (t < k) { ls[t] += ls[t+k]; lss[t] += lss[t+k]; }
    __syncthreads();
  }
  if (t == 0) {
    const float inv_n = 1.0f / 262144.0f;
    float mu  = ls[0] * inv_n;
    float var = fmaxf(lss[0] * inv_n - mu * mu, 0.0f);
    bn[c]     = mu;
    bn[C + c] = gv[c] / sqrtf(var + EPS_F);
  }
}

// ---------------------------------------------------------------- 5b. In-place BN2+GELU activation
__global__ __launch_bounds__(256) void act_kernel(float* __restrict__ h,
                                                  const float* __restrict__ bnp,
                                                  const float* __restrict__ btp)
{
  int p = blockIdx.x * 256 + threadIdx.x;
  float* row = h + (size_t)p * 64;
#pragma unroll
  for (int j = 0; j < 64; j += 4) {
    float4 v = *(const float4*)(row + j);
    v.x = gelu_f((v.x - bnp[j+0]) * bnp[64+j+0] + btp[j+0]);
    v.y = gelu_f((v.y - bnp[j+1]) * bnp[64+j+1] + btp[j+1]);
    v.z = gelu_f((v.z - bnp[j+2]) * bnp[64+j+2] + btp[j+2]);
    v.w = gelu_f((v.w - bnp[j+3]) * bnp[64+j+3] + btp[j+3]);
    *(float4*)(row + j) = v;
  }
}

// ---------------------------------------------------------------- 6a. Layer-3 stats (small-ws path; R10-verified)
__global__ __launch_bounds__(256, 1) void l3stats_kernel(
    const float* __restrict__ g2, const float* __restrict__ W3,
    const float* __restrict__ b3, float* __restrict__ part)
{
  int t = threadIdx.x;
  int gb = blockIdx.x >> 2, chunk = blockIdx.x & 3;
  int og0 = chunk * 32;
  int p = gb * 256 + t;
  const float* row = g2 + (size_t)p * 64;
  float in[64];
#pragma unroll
  for (int j = 0; j < 64; j += 4) {
    float4 v = *(const float4*)(row + j);
    in[j+0] = v.x; in[j+1] = v.y; in[j+2] = v.z; in[j+3] = v.w;
  }
  float s_[32], q_[32];
  for (int o4 = 0; o4 < 8; ++o4) {
    const float* w0 = W3 + (size_t)(og0 + o4 * 4) * 64;
    float a0 = b3[og0+o4*4+0], a1 = b3[og0+o4*4+1], a2 = b3[og0+o4*4+2], a3 = b3[og0+o4*4+3];
#pragma unroll
    for (int j = 0; j < 64; ++j) {
      float x = in[j];
      a0 = fmaf(x, w0[j],      a0);
      a1 = fmaf(x, w0[64+j],   a1);
      a2 = fmaf(x, w0[128+j],  a2);
      a3 = fmaf(x, w0[192+j],  a3);
    }
    int o = o4 * 4;
    s_[o]=a0; s_[o+1]=a1; s_[o+2]=a2; s_[o+3]=a3;
    q_[o]=a0*a0; q_[o+1]=a1*a1; q_[o+2]=a2*a2; q_[o+3]=a3*a3;
  }

  int wv = t >> 6, lane = t & 63;
  tree_step<1,16>(s_, q_, lane);
  tree_step<2, 8>(s_, q_, lane);
  tree_step<4, 4>(s_, q_, lane);
  tree_step<8, 2>(s_, q_, lane);
  tree_step<16,1>(s_, q_, lane);
  s_[0] += __shfl_xor(s_[0], 32, 64);
  q_[0] += __shfl_xor(q_[0], 32, 64);

  int ch = (int)(__brev((unsigned)(lane & 31)) >> 27);
  float* pw = part + ((size_t)blockIdx.x * 4 + wv) * 64;
  if (lane < 32) { pw[ch] = s_[0]; pw[32 + ch] = q_[0]; }
}

// ---------------------------------------------------------------- 6b. Layer-3 stats + h3t f16 emit (big-ws path)
// Reads PRE-ACTIVATED g2 (act_kernel ran first — R14 lesson: don't fuse gelu
// into a 4-chunk kernel). Emits h3t[gm][oc][k] f16 while accumulating stats.
__global__ __launch_bounds__(256, 1) void l3stats_h3_kernel(
    const float* __restrict__ g2, const float* __restrict__ W3,
    const float* __restrict__ b3, float* __restrict__ part,
    __half* __restrict__ h3t)
{
  int t = threadIdx.x;
  int gb = blockIdx.x >> 2, chunk = blockIdx.x & 3;
  int og0 = chunk * 32;
  int p = gb * 256 + t;
  const float* row = g2 + (size_t)p * 64;
  float in[64];
#pragma unroll
  for (int j = 0; j < 64; j += 4) {
    float4 v = *(const float4*)(row + j);
    in[j+0] = v.x; in[j+1] = v.y; in[j+2] = v.z; in[j+3] = v.w;
  }
  int gm = p >> 5, kk = p & 31;
  __half* hb = h3t + ((size_t)gm * 128 + og0) * 32 + kk;
  float s_[32], q_[32];
  for (int o4 = 0; o4 < 8; ++o4) {
    const float* w0 = W3 + (size_t)(og0 + o4 * 4) * 64;
    float a0 = b3[og0+o4*4+0], a1 = b3[og0+o4*4+1], a2 = b3[og0+o4*4+2], a3 = b3[og0+o4*4+3];
#pragma unroll
    for (int j = 0; j < 64; ++j) {
      float x = in[j];
      a0 = fmaf(x, w0[j],      a0);
      a1 = fmaf(x, w0[64+j],   a1);
      a2 = fmaf(x, w0[128+j],  a2);
      a3 = fmaf(x, w0[192+j],  a3);
    }
    int o = o4 * 4;
    hb[(size_t)(o+0)*32] = __float2half_rn(a0);
    hb[(size_t)(o+1)*32] = __float2half_rn(a1);
    hb[(size_t)(o+2)*32] = __float2half_rn(a2);
    hb[(size_t)(o+3)*32] = __float2half_rn(a3);
    s_[o]=a0; s_[o+1]=a1; s_[o+2]=a2; s_[o+3]=a3;
    q_[o]=a0*a0; q_[o+1]=a1*a1; q_[o+2]=a2*a2; q_[o+3]=a3*a3;
  }

  int wv = t >> 6, lane = t & 63;
  tree_step<1,16>(s_, q_, lane);
  tree_step<2, 8>(s_, q_, lane);
  tree_step<4, 4>(s_, q_, lane);
  tree_step<8, 2>(s_, q_, lane);
  tree_step<16,1>(s_, q_, lane);
  s_[0] += __shfl_xor(s_[0], 32, 64);
  q_[0] += __shfl_xor(q_[0], 32, 64);

  int ch = (int)(__brev((unsigned)(lane & 31)) >> 27);
  float* pw = part + ((size_t)blockIdx.x * 4 + wv) * 64;
  if (lane < 32) { pw[ch] = s_[0]; pw[32 + ch] = q_[0]; }
}

__global__ __launch_bounds__(256) void fin3_kernel(const float* __restrict__ part,
                                                   const float* __restrict__ gv,
                                                   float* __restrict__ bn)
{
  int c = blockIdx.x, t = threadIdx.x;
  int chunk = c >> 5, j = c & 31;
  float s = 0.0f, ss = 0.0f;
  for (int gb = t; gb < 1024; gb += 256) {
    int blk = gb * 4 + chunk;
#pragma unroll
    for (int wv = 0; wv < 4; ++wv) {
      const float* pw = part + ((size_t)blk * 4 + wv) * 64;
      s  += pw[j];
      ss += pw[32 + j];
    }
  }
  __shared__ float ls[256], lss[256];
  ls[t] = s; lss[t] = ss;
  __syncthreads();
  for (int k = 128; k > 0; k >>= 1) {
    if (t < k) { ls[t] += ls[t+k]; lss[t] += lss[t+k]; }
    __syncthreads();
  }
  if (t == 0) {
    const float inv_n = 1.0f / 262144.0f;
    float mu  = ls[0] * inv_n;
    float var = fmaxf(lss[0] * inv_n - mu * mu, 0.0f);
    bn[c]       = mu;
    bn[128 + c] = gv[c] / sqrtf(var + EPS_F);
  }
}

// ---------------------------------------------------------------- 7a. pool3 (small-ws path; R10-verified recompute)
__global__ __launch_bounds__(256, 1) void pool3_kernel(
    const float* __restrict__ g2, const float* __restrict__ W3,
    const float* __restrict__ b3,
    const float* __restrict__ bnp3,
    const float* __restrict__ btp3,
    float* __restrict__ out1)
{
  int t = threadIdx.x;
  int gb = blockIdx.x >> 2, chunk = blockIdx.x & 3;
  int og0 = chunk * 32;
  int p = gb * 256 + t;
  const float* row = g2 + (size_t)p * 64;
  float in[64];
#pragma unroll
  for (int j = 0; j < 64; j += 4) {
    float4 v = *(const float4*)(row + j);
    in[j+0] = v.x; in[j+1] = v.y; in[j+2] = v.z; in[j+3] = v.w;
  }
  float g_[32];
  for (int o4 = 0; o4 < 8; ++o4) {
    const float* w0 = W3 + (size_t)(og0 + o4 * 4) * 64;
    float a0 = b3[og0+o4*4+0], a1 = b3[og0+o4*4+1], a2 = b3[og0+o4*4+2], a3 = b3[og0+o4*4+3];
#pragma unroll
    for (int j = 0; j < 64; ++j) {
      float x = in[j];
      a0 = fmaf(x, w0[j],      a0);
      a1 = fmaf(x, w0[64+j],   a1);
      a2 = fmaf(x, w0[128+j],  a2);
      a3 = fmaf(x, w0[192+j],  a3);
    }
    int oc0 = og0 + o4 * 4, o = o4 * 4;
    g_[o]   = gelu_f((a0 - bnp3[oc0+0]) * bnp3[128+oc0+0] + btp3[oc0+0]);
    g_[o+1] = gelu_f((a1 - bnp3[oc0+1]) * bnp3[128+oc0+1] + btp3[oc0+1]);
    g_[o+2] = gelu_f((a2 - bnp3[oc0+2]) * bnp3[128+oc0+2] + btp3[oc0+2]);
    g_[o+3] = gelu_f((a3 - bnp3[oc0+3]) * bnp3[128+oc0+3] + btp3[oc0+3]);
  }

  ptree_step<1,16>(g_, t);
  ptree_step<2, 8>(g_, t);
  ptree_step<4, 4>(g_, t);
  ptree_step<8, 2>(g_, t);
  ptree_step<16,1>(g_, t);

  int ch = (int)(__brev((unsigned)(t & 31)) >> 27);
  int gm = gb * 8 + (t >> 5);
  out1[(size_t)gm * 128 + og0 + ch] = g_[0];
}

// ---------------------------------------------------------------- 7b. pool3t (big-ws path): read h3t f16, BN3+GELU+max
__global__ __launch_bounds__(256) void pool3t_kernel(
    const __half* __restrict__ h3t,
    const float* __restrict__ bnp3, const float* __restrict__ btp3,
    float* __restrict__ out1)
{
  int u = blockIdx.x * 256 + threadIdx.x;      // 0..1048575
  int gm = u >> 7, oc = u & 127;
  float mu = bnp3[oc], a = bnp3[128 + oc], bt = btp3[oc];
  const uint4* src = (const uint4*)(h3t + ((size_t)gm * 128 + oc) * 32);
  float mx = -__builtin_inff();
#pragma unroll
  for (int i = 0; i < 4; ++i) {
    uint4 v = src[i];
    unsigned wds[4] = {v.x, v.y, v.z, v.w};
#pragma unroll
    for (int w2 = 0; w2 < 4; ++w2) {
      __half2 hp = *reinterpret_cast<const __half2*>(&wds[w2]);
      float2 f = __half22float2(hp);
      float x0 = gelu_f((f.x - mu) * a + bt);
      float x1 = gelu_f((f.y - mu) * a + bt);
      mx = fmaxf(mx, fmaxf(x0, x1));
    }
  }
  out1[u] = mx;
}

// ---------------------------------------------------------------- diagnostic fill
__global__ void fill_kernel(float* __restrict__ out1) {
  out1[blockIdx.x * 256 + threadIdx.x] = 1.0e6f;
}

// ---------------------------------------------------------------- launch
extern "C" void kernel_launch(void* const* d_in, const int* in_sizes, int n_in,
                              void* d_out, int out_size, void* d_ws, size_t ws_size,
                              hipStream_t stream)
{
  (void)in_sizes; (void)n_in; (void)out_size;
  const float* xyz   = (const float*)d_in[0];
  const float* feats = (const float*)d_in[1];
  const float* W1  = (const float*)d_in[2];
  const float* b1  = (const float*)d_in[3];
  const float* g1  = (const float*)d_in[4];
  const float* bt1 = (const float*)d_in[5];
  const float* W2  = (const float*)d_in[6];
  const float* b2  = (const float*)d_in[7];
  const float* g2  = (const float*)d_in[8];
  const float* bt2 = (const float*)d_in[9];
  const float* W3  = (const float*)d_in[10];
  const float* b3  = (const float*)d_in[11];
  const float* g3  = (const float*)d_in[12];
  const float* bt3 = (const float*)d_in[13];

  float* out0 = (float*)d_out;
  float* out1 = out0 + (size_t)BATCH * MCENT * 3;

  char* ws = (char*)d_ws;
  int*   gidx    = (int*)(ws + 0);
  float* part    = (float*)(ws + (1u << 20));
  float* bn0     = (float*)(ws + 5u * (1u << 20));
  float* bn1     = bn0 + 128;
  float* bn2     = bn0 + 256;
  float* dist_ws = (float*)(ws + 5u * (1u << 20) + 65536u);
  float* cst     = (float*)(ws + 5u * (1u << 20) + 65536u + 262144u);
  float* h1      = (float*)(ws + 6u * (1u << 20));
  __half* h3t    = (__half*)(ws + 70u * (1u << 20));

  if (ws_size < WS_NEED_SMALL) {
    fill_kernel<<<4096, 256, 0, stream>>>(out1);
    return;
  }

  // 19 dispatches: FPS phases 0..15; bq lags 1, l1 lags 2, L1-stats lags 3.
  for (int s0 = 0; s0 <= MCENT + 2 * FPS_STEPS; s0 += FPS_STEPS)
    mega_kernel<<<136, 512, 0, stream>>>(xyz, out0, dist_ws, cst, s0,
                                         gidx, feats, W1, b1, h1, part);

  fin_kernel<64><<<64, 256, 0, stream>>>(part, g1, bn0);
  l2_kernel<<<1024, 256, 0, stream>>>(h1, W2, b2, bn0, bt1);
  stats_kernel<64><<<512, 256, 0, stream>>>(h1, part);
  fin_kernel<64><<<64, 256, 0, stream>>>(part, g2, bn1);
  act_kernel<<<1024, 256, 0, stream>>>(h1, bn1, bt2);          // h1 -> gelu'd g2

  if (ws_size >= WS_NEED_BIG) {
    // big-ws path: f16 h3 materialization + light pool (R14 win, act restored).
    l3stats_h3_kernel<<<4096, 256, 0, stream>>>(h1, W3, b3, part, h3t);
    fin3_kernel<<<128, 256, 0, stream>>>(part, g3, bn2);
    pool3t_kernel<<<4096, 256, 0, stream>>>(h3t, bn2, bt3, out1);
  } else {
    // small-ws fallback: R13-verified sequence.
    l3stats_kernel<<<4096, 256, 0, stream>>>(h1, W3, b3, part);
    fin3_kernel<<<128, 256, 0, stream>>>(part, g3, bn2);
    pool3_kernel<<<4096, 256, 0, stream>>>(h1, W3, b3, bn2, bt3, out1);
  }
}